// Round 1
// baseline (5488.500 us; speedup 1.0000x reference)
//
#include <hip/hip_runtime.h>
#include <math.h>

// Problem constants
#define LPOS 4096      // 64*64 positions / patches
#define KPAT 576       // 64ch * 3*3 patch
#define RPAT 2048      // 128ch * 4*4 raw patch

// ---------------------------------------------------------------------------
// Build P[pos][576] = 3x3x64 patches of x2[b] (zero pad 1), and rnorm[pos]
__global__ __launch_bounds__(64) void build_P_norm(const float* __restrict__ x2b,
                                                   float* __restrict__ P,
                                                   float* __restrict__ rnorm) {
    int pos = blockIdx.x;
    int u = pos >> 6, v = pos & 63;
    int tid = threadIdx.x;
    float ss = 0.f;
    for (int k = tid; k < KPAT; k += 64) {
        int c = k / 9, r9 = k % 9;
        int di = r9 / 3, dj = r9 % 3;
        int yy = u + di - 1, xx = v + dj - 1;
        float val = 0.f;
        if (yy >= 0 && yy < 64 && xx >= 0 && xx < 64)
            val = x2b[c * 4096 + yy * 64 + xx];
        P[pos * KPAT + k] = val;
        ss += val * val;
    }
#pragma unroll
    for (int off = 32; off; off >>= 1) ss += __shfl_xor(ss, off, 64);
    if (tid == 0) rnorm[pos] = 1.f / fmaxf(sqrtf(ss), 1e-4f);
}

// ---------------------------------------------------------------------------
// mi[pos] = 1 if 4x4 (stride2, pad1) patch of mask[b] is all-zero else 0
__global__ __launch_bounds__(256) void build_mi(const float* __restrict__ maskb,
                                                float* __restrict__ mi) {
    int pos = blockIdx.x * 256 + threadIdx.x;
    if (pos >= LPOS) return;
    int pu = pos >> 6, pv = pos & 63;
    float s = 0.f;
    for (int t = 0; t < 4; ++t)
        for (int w = 0; w < 4; ++w) {
            int yy = 2 * pu - 1 + t, xx = 2 * pv - 1 + w;
            if (yy >= 0 && yy < 128 && xx >= 0 && xx < 128) s += maskb[yy * 128 + xx];
        }
    mi[pos] = (s == 0.f) ? 1.f : 0.f;
}

// ---------------------------------------------------------------------------
// S[pos][p] = dot(P[pos], P[p]) * rnorm[p]    M=N=4096, K=576
__global__ __launch_bounds__(256) void gemm_score(const float* __restrict__ P,
                                                  const float* __restrict__ rnorm,
                                                  float* __restrict__ S) {
    __shared__ __align__(16) float As[16][68];
    __shared__ __align__(16) float Bs[16][68];
    int tid = threadIdx.x;
    int tx = tid & 15, ty = tid >> 4;
    int m0 = blockIdx.y * 64, n0 = blockIdx.x * 64;
    float acc[4][4] = {};
    int lm = tid >> 2;            // 0..63 tile row
    int lk = (tid & 3) * 4;       // 0,4,8,12
    const float* Arow = P + (size_t)(m0 + lm) * KPAT + lk;
    const float* Brow = P + (size_t)(n0 + lm) * KPAT + lk;
    for (int k0 = 0; k0 < KPAT; k0 += 16) {
        float4 av = *(const float4*)(Arow + k0);
        float4 bv = *(const float4*)(Brow + k0);
        As[lk + 0][lm] = av.x; As[lk + 1][lm] = av.y; As[lk + 2][lm] = av.z; As[lk + 3][lm] = av.w;
        Bs[lk + 0][lm] = bv.x; Bs[lk + 1][lm] = bv.y; Bs[lk + 2][lm] = bv.z; Bs[lk + 3][lm] = bv.w;
        __syncthreads();
#pragma unroll
        for (int kk = 0; kk < 16; ++kk) {
            float4 a = *(const float4*)&As[kk][ty * 4];
            float4 b = *(const float4*)&Bs[kk][tx * 4];
            acc[0][0] += a.x * b.x; acc[0][1] += a.x * b.y; acc[0][2] += a.x * b.z; acc[0][3] += a.x * b.w;
            acc[1][0] += a.y * b.x; acc[1][1] += a.y * b.y; acc[1][2] += a.y * b.z; acc[1][3] += a.y * b.w;
            acc[2][0] += a.z * b.x; acc[2][1] += a.z * b.y; acc[2][2] += a.z * b.z; acc[2][3] += a.z * b.w;
            acc[3][0] += a.w * b.x; acc[3][1] += a.w * b.y; acc[3][2] += a.w * b.z; acc[3][3] += a.w * b.w;
        }
        __syncthreads();
    }
    float4 rn = *(const float4*)&rnorm[n0 + tx * 4];
#pragma unroll
    for (int i = 0; i < 4; ++i) {
        float4 o;
        o.x = acc[i][0] * rn.x; o.y = acc[i][1] * rn.y; o.z = acc[i][2] * rn.z; o.w = acc[i][3] * rn.w;
        *(float4*)&S[(size_t)(m0 + ty * 4 + i) * LPOS + n0 + tx * 4] = o;
    }
}

// ---------------------------------------------------------------------------
// In-place masked softmax over p for each pos row; then * mi[p] * ma[pos]
__global__ __launch_bounds__(256) void softmax_mask(float* __restrict__ S,
                                                    const float* __restrict__ mi,
                                                    const float* __restrict__ mab) {
    int pos = blockIdx.x;
    int tid = threadIdx.x;
    float ma = mab[pos];
    float sc = 10.0f * ma;
    float v[16];
    float vmax = -1e30f;
#pragma unroll
    for (int i = 0; i < 16; ++i) {
        int p = tid + i * 256;
        float x = S[(size_t)pos * LPOS + p] * mi[p] * sc;
        v[i] = x;
        vmax = fmaxf(vmax, x);
    }
#pragma unroll
    for (int off = 32; off; off >>= 1) vmax = fmaxf(vmax, __shfl_xor(vmax, off, 64));
    __shared__ float sred[4];
    int wid = tid >> 6;
    if ((tid & 63) == 0) sred[wid] = vmax;
    __syncthreads();
    vmax = fmaxf(fmaxf(sred[0], sred[1]), fmaxf(sred[2], sred[3]));
    __syncthreads();
    float ssum = 0.f;
#pragma unroll
    for (int i = 0; i < 16; ++i) {
        float e = expf(v[i] - vmax);
        v[i] = e;
        ssum += e;
    }
#pragma unroll
    for (int off = 32; off; off >>= 1) ssum += __shfl_xor(ssum, off, 64);
    if ((tid & 63) == 0) sred[wid] = ssum;
    __syncthreads();
    float inv = 1.f / (sred[0] + sred[1] + sred[2] + sred[3]);
#pragma unroll
    for (int i = 0; i < 16; ++i) {
        int p = tid + i * 256;
        S[(size_t)pos * LPOS + p] = v[i] * inv * mi[p] * ma;
    }
}

// ---------------------------------------------------------------------------
// R[p][c*16 + t*4 + s] = x1[b][c][2pu-1+t][2pv-1+s]  (zero pad)
__global__ __launch_bounds__(256) void build_R(const float* __restrict__ x1b,
                                               float* __restrict__ R) {
    int pos = blockIdx.x;
    int pu = pos >> 6, pv = pos & 63;
    int tid = threadIdx.x;
#pragma unroll
    for (int i = 0; i < 8; ++i) {
        int idx = tid + i * 256;
        int c = idx >> 4, rr = idx & 15;
        int t = rr >> 2, s = rr & 3;
        int yy = 2 * pu - 1 + t, xx = 2 * pv - 1 + s;
        float val = 0.f;
        if (yy >= 0 && yy < 128 && xx >= 0 && xx < 128)
            val = x1b[c * 16384 + yy * 128 + xx];
        R[(size_t)pos * RPAT + idx] = val;
    }
}

// ---------------------------------------------------------------------------
// V[pos][n] = sum_p A[pos][p] * R[p][n]   M=4096, N=2048, K=4096
__global__ __launch_bounds__(256) void gemm_deconv(const float* __restrict__ A,
                                                   const float* __restrict__ R,
                                                   float* __restrict__ V) {
    __shared__ __align__(16) float As[16][68];
    __shared__ __align__(16) float Bs[16][68];
    int tid = threadIdx.x;
    int tx = tid & 15, ty = tid >> 4;
    int m0 = blockIdx.y * 64, n0 = blockIdx.x * 64;
    float acc[4][4] = {};
    int lm = tid >> 2;
    int lk = (tid & 3) * 4;
    const float* Arow = A + (size_t)(m0 + lm) * LPOS + lk;
    int bkk = tid >> 4;           // 0..15 B-tile row
    int bn4 = (tid & 15) * 4;     // 0..60 B-tile col
    for (int k0 = 0; k0 < LPOS; k0 += 16) {
        float4 av = *(const float4*)(Arow + k0);
        float4 bv = *(const float4*)&R[(size_t)(k0 + bkk) * RPAT + n0 + bn4];
        As[lk + 0][lm] = av.x; As[lk + 1][lm] = av.y; As[lk + 2][lm] = av.z; As[lk + 3][lm] = av.w;
        *(float4*)&Bs[bkk][bn4] = bv;
        __syncthreads();
#pragma unroll
        for (int kk = 0; kk < 16; ++kk) {
            float4 a = *(const float4*)&As[kk][ty * 4];
            float4 b = *(const float4*)&Bs[kk][tx * 4];
            acc[0][0] += a.x * b.x; acc[0][1] += a.x * b.y; acc[0][2] += a.x * b.z; acc[0][3] += a.x * b.w;
            acc[1][0] += a.y * b.x; acc[1][1] += a.y * b.y; acc[1][2] += a.y * b.z; acc[1][3] += a.y * b.w;
            acc[2][0] += a.z * b.x; acc[2][1] += a.z * b.y; acc[2][2] += a.z * b.z; acc[2][3] += a.z * b.w;
            acc[3][0] += a.w * b.x; acc[3][1] += a.w * b.y; acc[3][2] += a.w * b.z; acc[3][3] += a.w * b.w;
        }
        __syncthreads();
    }
#pragma unroll
    for (int i = 0; i < 4; ++i) {
        float4 o;
        o.x = acc[i][0]; o.y = acc[i][1]; o.z = acc[i][2]; o.w = acc[i][3];
        *(float4*)&V[(size_t)(m0 + ty * 4 + i) * RPAT + n0 + tx * 4] = o;
    }
}

// ---------------------------------------------------------------------------
// y[c][yy][xx] = 0.25 * sum over valid (t,u),(s,v): V[(u*64+v)][c*16+t*4+s]
__global__ __launch_bounds__(256) void reconstruct(const float* __restrict__ V,
                                                   float* __restrict__ yb) {
    int idx = blockIdx.x * 256 + threadIdx.x;   // c*16384 + yy*128 + xx
    int xx = idx & 127, yy = (idx >> 7) & 127, c = idx >> 14;
    float sum = 0.f;
    int tbase_y = (yy & 1) ? 0 : 1;
    int tbase_x = (xx & 1) ? 0 : 1;
#pragma unroll
    for (int dt = 0; dt < 2; ++dt) {
        int t = tbase_y + 2 * dt;
        int u2 = yy + 1 - t;
        if (u2 < 0 || u2 >= 128) continue;
        int u = u2 >> 1;
#pragma unroll
        for (int ds = 0; ds < 2; ++ds) {
            int s = tbase_x + 2 * ds;
            int v2 = xx + 1 - s;
            if (v2 < 0 || v2 >= 128) continue;
            int v = v2 >> 1;
            sum += V[(size_t)(u * 64 + v) * RPAT + c * 16 + t * 4 + s];
        }
    }
    yb[idx] = 0.25f * sum;
}

// ---------------------------------------------------------------------------
// Grouped dilated 3x3 convs + bias + relu.  grid (64 tiles, 4 groups), 256 thr
__global__ __launch_bounds__(256) void final_conv(const float* __restrict__ yb,
                                                  const float* __restrict__ cw,
                                                  const float* __restrict__ cb,
                                                  float* __restrict__ out, int b) {
    int g = blockIdx.y;
    int tile = blockIdx.x;
    int ty0 = (tile >> 3) << 4, tx0 = (tile & 7) << 4;
    int tid = threadIdx.x;
    int ly = tid >> 4, lx = tid & 15;
    int yy = ty0 + ly, xx = tx0 + lx;
    int r = 1 << g;   // RATES = 1,2,4,8
    __shared__ float ws[144];
    float acc[16];
#pragma unroll
    for (int i = 0; i < 16; ++i) acc[i] = 0.f;
    for (int c = 0; c < 128; ++c) {
        __syncthreads();
        if (tid < 144) {
            int oc = tid / 9, kk = tid % 9;
            ws[tid] = cw[((g * 16 + oc) * 128 + c) * 9 + kk];
        }
        __syncthreads();
        float in[9];
#pragma unroll
        for (int kh = 0; kh < 3; ++kh)
#pragma unroll
            for (int kw = 0; kw < 3; ++kw) {
                int iy = yy + (kh - 1) * r, ix = xx + (kw - 1) * r;
                in[kh * 3 + kw] = (iy >= 0 && iy < 128 && ix >= 0 && ix < 128)
                                      ? yb[c * 16384 + iy * 128 + ix] : 0.f;
            }
#pragma unroll
        for (int oc = 0; oc < 16; ++oc) {
            float a = acc[oc];
#pragma unroll
            for (int k = 0; k < 9; ++k) a += in[k] * ws[oc * 9 + k];
            acc[oc] = a;
        }
    }
#pragma unroll
    for (int oc = 0; oc < 16; ++oc) {
        float vv = acc[oc] + cb[g * 16 + oc];
        out[(size_t)((b * 64 + g * 16 + oc)) * 16384 + yy * 128 + xx] = fmaxf(vv, 0.f);
    }
}

// ---------------------------------------------------------------------------
extern "C" void kernel_launch(void* const* d_in, const int* in_sizes, int n_in,
                              void* d_out, int out_size, void* d_ws, size_t ws_size,
                              hipStream_t stream) {
    const float* x1 = (const float*)d_in[0];        // (4,128,128,128)
    const float* x2 = (const float*)d_in[1];        // (4,64,64,64)
    const float* mask = (const float*)d_in[2];      // (4,1,128,128)
    const float* mask_all = (const float*)d_in[3];  // (4,1,64,64)
    const float* conv_w = (const float*)d_in[4];    // (4,16,128,3,3)
    const float* conv_b = (const float*)d_in[5];    // (4,16)
    float* out = (float*)d_out;                     // (4,64,128,128)

    char* ws = (char*)d_ws;
    float* P     = (float*)(ws + 0);           //  9,437,184 B
    float* rnorm = (float*)(ws + 9437184);     //     16,384 B
    float* mi    = (float*)(ws + 9453568);     //     16,384 B
    float* S     = (float*)(ws + 9469952);     // 67,108,864 B
    float* R     = (float*)(ws + 76578816);    // 33,554,432 B
    float* V     = (float*)(ws + 110133248);   // 33,554,432 B
    float* yb    = (float*)(ws + 143687680);   //  8,388,608 B  (end 152,076,288)

    for (int b = 0; b < 4; ++b) {
        const float* x2b = x2 + (size_t)b * 64 * 4096;
        const float* x1b = x1 + (size_t)b * 128 * 16384;
        build_P_norm<<<4096, 64, 0, stream>>>(x2b, P, rnorm);
        build_mi<<<16, 256, 0, stream>>>(mask + (size_t)b * 16384, mi);
        gemm_score<<<dim3(64, 64), 256, 0, stream>>>(P, rnorm, S);
        softmax_mask<<<4096, 256, 0, stream>>>(S, mi, mask_all + (size_t)b * 4096);
        build_R<<<4096, 256, 0, stream>>>(x1b, R);
        gemm_deconv<<<dim3(32, 64), 256, 0, stream>>>(S, R, V);
        reconstruct<<<8192, 256, 0, stream>>>(V, yb);
        final_conv<<<dim3(64, 4), 256, 0, stream>>>(yb, conv_w, conv_b, out, b);
    }
}

// Round 2
// 1601.269 us; speedup vs baseline: 3.4276x; 3.4276x over previous
//
#include <hip/hip_runtime.h>
#include <math.h>

typedef __bf16 bf16;
typedef __attribute__((ext_vector_type(8))) __bf16 bf16x8;
typedef __attribute__((ext_vector_type(4))) float f32x4;

#define LPOS 4096      // 64*64 positions / patches
#define KPAT 576       // 64ch * 3*3 patch
#define RPAT 2048      // 128ch * 4*4 raw patch

#define GLDS(g, l) __builtin_amdgcn_global_load_lds( \
    (const __attribute__((address_space(1))) void*)(g), \
    (__attribute__((address_space(3))) void*)(l), 16, 0, 0)

// ---------------------------------------------------------------------------
// Phi/Plo[pos][576] = split-bf16 of 3x3x64 patches of x2[b]; rnorm[pos]
__global__ __launch_bounds__(64) void build_P_norm(const float* __restrict__ x2b,
                                                   bf16* __restrict__ Phi,
                                                   bf16* __restrict__ Plo,
                                                   float* __restrict__ rnorm) {
    int pos = blockIdx.x;
    int u = pos >> 6, v = pos & 63;
    int tid = threadIdx.x;
    float ss = 0.f;
    for (int k = tid; k < KPAT; k += 64) {
        int c = k / 9, r9 = k % 9;
        int di = r9 / 3, dj = r9 % 3;
        int yy = u + di - 1, xx = v + dj - 1;
        float val = 0.f;
        if (yy >= 0 && yy < 64 && xx >= 0 && xx < 64)
            val = x2b[c * 4096 + yy * 64 + xx];
        bf16 hi = (bf16)val;
        Phi[pos * KPAT + k] = hi;
        Plo[pos * KPAT + k] = (bf16)(val - (float)hi);
        ss += val * val;
    }
#pragma unroll
    for (int off = 32; off; off >>= 1) ss += __shfl_xor(ss, off, 64);
    if (tid == 0) rnorm[pos] = 1.f / fmaxf(sqrtf(ss), 1e-4f);
}

// ---------------------------------------------------------------------------
__global__ __launch_bounds__(256) void build_mi(const float* __restrict__ maskb,
                                                float* __restrict__ mi) {
    int pos = blockIdx.x * 256 + threadIdx.x;
    if (pos >= LPOS) return;
    int pu = pos >> 6, pv = pos & 63;
    float s = 0.f;
    for (int t = 0; t < 4; ++t)
        for (int w = 0; w < 4; ++w) {
            int yy = 2 * pu - 1 + t, xx = 2 * pv - 1 + w;
            if (yy >= 0 && yy < 128 && xx >= 0 && xx < 128) s += maskb[yy * 128 + xx];
        }
    mi[pos] = (s == 0.f) ? 1.f : 0.f;
}

// ---------------------------------------------------------------------------
// S[m][n] = (Phi+Plo)[m] . (Phi+Plo)[n] * rnorm[n]  via 3-product split-bf16
// 128x128 tile, 4 waves, each wave 64x64 via 4x4 of 16x16x32 MFMA.
__global__ __launch_bounds__(256) void gemm_score_mfma(const bf16* __restrict__ Phi,
                                                       const bf16* __restrict__ Plo,
                                                       const float* __restrict__ rnorm,
                                                       float* __restrict__ S) {
    __shared__ bf16 Ah[128 * 32], Al[128 * 32], Bh[128 * 32], Bl[128 * 32];
    int tid = threadIdx.x;
    int w = tid >> 6, lane = tid & 63;
    int wy = w >> 1, wx = w & 1;
    int m0 = blockIdx.y * 128, n0 = blockIdx.x * 128;
    f32x4 acc[4][4];
#pragma unroll
    for (int mt = 0; mt < 4; ++mt)
#pragma unroll
        for (int nt = 0; nt < 4; ++nt) acc[mt][nt] = (f32x4){0.f, 0.f, 0.f, 0.f};
    int srow = lane >> 2;           // 0..15
    int scol = (lane & 3) * 8;      // element offset within 32-wide K tile
    int q = (lane >> 4) * 8, r = lane & 15;
    for (int k0 = 0; k0 < KPAT; k0 += 32) {
#pragma unroll
        for (int i = 0; i < 2; ++i) {
            int row = w * 32 + i * 16 + srow;
            int ldso = row * 32 + scol;
            GLDS(Phi + (size_t)(m0 + row) * KPAT + k0 + scol, Ah + ldso);
            GLDS(Plo + (size_t)(m0 + row) * KPAT + k0 + scol, Al + ldso);
            GLDS(Phi + (size_t)(n0 + row) * KPAT + k0 + scol, Bh + ldso);
            GLDS(Plo + (size_t)(n0 + row) * KPAT + k0 + scol, Bl + ldso);
        }
        __syncthreads();
        bf16x8 vbh[4], vbl[4];
#pragma unroll
        for (int nt = 0; nt < 4; ++nt) {
            int rb = (wx * 64 + nt * 16 + r) * 32 + q;
            vbh[nt] = *(const bf16x8*)&Bh[rb];
            vbl[nt] = *(const bf16x8*)&Bl[rb];
        }
#pragma unroll
        for (int mt = 0; mt < 4; ++mt) {
            int ra = (wy * 64 + mt * 16 + r) * 32 + q;
            bf16x8 vah = *(const bf16x8*)&Ah[ra];
            bf16x8 vlo = *(const bf16x8*)&Al[ra];
#pragma unroll
            for (int nt = 0; nt < 4; ++nt) {
                acc[mt][nt] = __builtin_amdgcn_mfma_f32_16x16x32_bf16(vah, vbh[nt], acc[mt][nt], 0, 0, 0);
                acc[mt][nt] = __builtin_amdgcn_mfma_f32_16x16x32_bf16(vah, vbl[nt], acc[mt][nt], 0, 0, 0);
                acc[mt][nt] = __builtin_amdgcn_mfma_f32_16x16x32_bf16(vlo, vbh[nt], acc[mt][nt], 0, 0, 0);
            }
        }
        __syncthreads();
    }
    int qq = lane >> 4;
#pragma unroll
    for (int nt = 0; nt < 4; ++nt) {
        int col = n0 + wx * 64 + nt * 16 + r;
        float rn = rnorm[col];
#pragma unroll
        for (int mt = 0; mt < 4; ++mt)
#pragma unroll
            for (int ri = 0; ri < 4; ++ri) {
                int row = m0 + wy * 64 + mt * 16 + qq * 4 + ri;
                S[(size_t)row * LPOS + col] = acc[mt][nt][ri] * rn;
            }
    }
}

// ---------------------------------------------------------------------------
// Masked softmax over p per row; writes bf16 attention matrix Abf
__global__ __launch_bounds__(256) void softmax_mask(const float* __restrict__ S,
                                                    const float* __restrict__ mi,
                                                    const float* __restrict__ mab,
                                                    bf16* __restrict__ Abf) {
    int pos = blockIdx.x;
    int tid = threadIdx.x;
    float ma = mab[pos];
    float sc = 10.0f * ma;
    float v[16];
    float vmax = -1e30f;
#pragma unroll
    for (int i = 0; i < 16; ++i) {
        int p = tid + i * 256;
        float x = S[(size_t)pos * LPOS + p] * mi[p] * sc;
        v[i] = x;
        vmax = fmaxf(vmax, x);
    }
#pragma unroll
    for (int off = 32; off; off >>= 1) vmax = fmaxf(vmax, __shfl_xor(vmax, off, 64));
    __shared__ float sred[4];
    int wid = tid >> 6;
    if ((tid & 63) == 0) sred[wid] = vmax;
    __syncthreads();
    vmax = fmaxf(fmaxf(sred[0], sred[1]), fmaxf(sred[2], sred[3]));
    __syncthreads();
    float ssum = 0.f;
#pragma unroll
    for (int i = 0; i < 16; ++i) {
        float e = expf(v[i] - vmax);
        v[i] = e;
        ssum += e;
    }
#pragma unroll
    for (int off = 32; off; off >>= 1) ssum += __shfl_xor(ssum, off, 64);
    if ((tid & 63) == 0) sred[wid] = ssum;
    __syncthreads();
    float inv = 1.f / (sred[0] + sred[1] + sred[2] + sred[3]);
#pragma unroll
    for (int i = 0; i < 16; ++i) {
        int p = tid + i * 256;
        Abf[(size_t)pos * LPOS + p] = (bf16)(v[i] * inv * mi[p] * ma);
    }
}

// ---------------------------------------------------------------------------
// Rt[n][p] = x1[b][c][2pu-1+t][2pv-1+s], n = c*16+t*4+s  (bf16, K-contiguous)
__global__ __launch_bounds__(256) void build_Rt(const float* __restrict__ x1b,
                                                bf16* __restrict__ Rt) {
    int idx = blockIdx.x * 256 + threadIdx.x;   // n*4096 + p
    int p = idx & 4095, n = idx >> 12;
    int pu = p >> 6, pv = p & 63;
    int c = n >> 4, t = (n >> 2) & 3, s = n & 3;
    int yy = 2 * pu - 1 + t, xx = 2 * pv - 1 + s;
    float val = 0.f;
    if (yy >= 0 && yy < 128 && xx >= 0 && xx < 128)
        val = x1b[c * 16384 + yy * 128 + xx];
    Rt[idx] = (bf16)val;
}

// ---------------------------------------------------------------------------
// V[m][n] = sum_k A[m][k] * Bt[n][k]   M=4096, N=2048, K=4096 (bf16 MFMA)
__global__ __launch_bounds__(256) void gemm_deconv_mfma(const bf16* __restrict__ A,
                                                        const bf16* __restrict__ Bt,
                                                        float* __restrict__ V) {
    __shared__ bf16 As[128 * 32], Bs[128 * 32];
    int tid = threadIdx.x;
    int w = tid >> 6, lane = tid & 63;
    int wy = w >> 1, wx = w & 1;
    int m0 = blockIdx.y * 128, n0 = blockIdx.x * 128;
    f32x4 acc[4][4];
#pragma unroll
    for (int mt = 0; mt < 4; ++mt)
#pragma unroll
        for (int nt = 0; nt < 4; ++nt) acc[mt][nt] = (f32x4){0.f, 0.f, 0.f, 0.f};
    int srow = lane >> 2;
    int scol = (lane & 3) * 8;
    int q = (lane >> 4) * 8, r = lane & 15;
    for (int k0 = 0; k0 < LPOS; k0 += 32) {
#pragma unroll
        for (int i = 0; i < 2; ++i) {
            int row = w * 32 + i * 16 + srow;
            int ldso = row * 32 + scol;
            GLDS(A + (size_t)(m0 + row) * LPOS + k0 + scol, As + ldso);
            GLDS(Bt + (size_t)(n0 + row) * LPOS + k0 + scol, Bs + ldso);
        }
        __syncthreads();
        bf16x8 vb[4];
#pragma unroll
        for (int nt = 0; nt < 4; ++nt)
            vb[nt] = *(const bf16x8*)&Bs[(wx * 64 + nt * 16 + r) * 32 + q];
#pragma unroll
        for (int mt = 0; mt < 4; ++mt) {
            bf16x8 va = *(const bf16x8*)&As[(wy * 64 + mt * 16 + r) * 32 + q];
#pragma unroll
            for (int nt = 0; nt < 4; ++nt)
                acc[mt][nt] = __builtin_amdgcn_mfma_f32_16x16x32_bf16(va, vb[nt], acc[mt][nt], 0, 0, 0);
        }
        __syncthreads();
    }
    int qq = lane >> 4;
#pragma unroll
    for (int mt = 0; mt < 4; ++mt)
#pragma unroll
        for (int nt = 0; nt < 4; ++nt) {
            int col = n0 + wx * 64 + nt * 16 + r;
#pragma unroll
            for (int ri = 0; ri < 4; ++ri) {
                int row = m0 + wy * 64 + mt * 16 + qq * 4 + ri;
                V[(size_t)row * RPAT + col] = acc[mt][nt][ri];
            }
        }
}

// ---------------------------------------------------------------------------
// y[c][yy][xx] = 0.25 * sum over valid taps of V
__global__ __launch_bounds__(256) void reconstruct(const float* __restrict__ V,
                                                   float* __restrict__ yb) {
    int idx = blockIdx.x * 256 + threadIdx.x;   // c*16384 + yy*128 + xx
    int xx = idx & 127, yy = (idx >> 7) & 127, c = idx >> 14;
    float sum = 0.f;
    int tbase_y = (yy & 1) ? 0 : 1;
    int tbase_x = (xx & 1) ? 0 : 1;
#pragma unroll
    for (int dt = 0; dt < 2; ++dt) {
        int t = tbase_y + 2 * dt;
        int u2 = yy + 1 - t;
        if (u2 < 0 || u2 >= 128) continue;
        int u = u2 >> 1;
#pragma unroll
        for (int ds = 0; ds < 2; ++ds) {
            int s = tbase_x + 2 * ds;
            int v2 = xx + 1 - s;
            if (v2 < 0 || v2 >= 128) continue;
            int v = v2 >> 1;
            sum += V[(size_t)(u * 64 + v) * RPAT + c * 16 + t * 4 + s];
        }
    }
    yb[idx] = 0.25f * sum;
}

// ---------------------------------------------------------------------------
// Grouped dilated 3x3 convs + bias + relu
__global__ __launch_bounds__(256) void final_conv(const float* __restrict__ yb,
                                                  const float* __restrict__ cw,
                                                  const float* __restrict__ cb,
                                                  float* __restrict__ out, int b) {
    int g = blockIdx.y;
    int tile = blockIdx.x;
    int ty0 = (tile >> 3) << 4, tx0 = (tile & 7) << 4;
    int tid = threadIdx.x;
    int ly = tid >> 4, lx = tid & 15;
    int yy = ty0 + ly, xx = tx0 + lx;
    int rr = 1 << g;   // RATES = 1,2,4,8
    __shared__ float ws[144];
    float acc[16];
#pragma unroll
    for (int i = 0; i < 16; ++i) acc[i] = 0.f;
    for (int c = 0; c < 128; ++c) {
        __syncthreads();
        if (tid < 144) {
            int oc = tid / 9, kk = tid % 9;
            ws[tid] = cw[((g * 16 + oc) * 128 + c) * 9 + kk];
        }
        __syncthreads();
        float in[9];
#pragma unroll
        for (int kh = 0; kh < 3; ++kh)
#pragma unroll
            for (int kw = 0; kw < 3; ++kw) {
                int iy = yy + (kh - 1) * rr, ix = xx + (kw - 1) * rr;
                in[kh * 3 + kw] = (iy >= 0 && iy < 128 && ix >= 0 && ix < 128)
                                      ? yb[c * 16384 + iy * 128 + ix] : 0.f;
            }
#pragma unroll
        for (int oc = 0; oc < 16; ++oc) {
            float a = acc[oc];
#pragma unroll
            for (int k = 0; k < 9; ++k) a += in[k] * ws[oc * 9 + k];
            acc[oc] = a;
        }
    }
#pragma unroll
    for (int oc = 0; oc < 16; ++oc) {
        float vv = acc[oc] + cb[g * 16 + oc];
        out[(size_t)((b * 64 + g * 16 + oc)) * 16384 + yy * 128 + xx] = fmaxf(vv, 0.f);
    }
}

// ---------------------------------------------------------------------------
extern "C" void kernel_launch(void* const* d_in, const int* in_sizes, int n_in,
                              void* d_out, int out_size, void* d_ws, size_t ws_size,
                              hipStream_t stream) {
    const float* x1 = (const float*)d_in[0];        // (4,128,128,128)
    const float* x2 = (const float*)d_in[1];        // (4,64,64,64)
    const float* mask = (const float*)d_in[2];      // (4,1,128,128)
    const float* mask_all = (const float*)d_in[3];  // (4,1,64,64)
    const float* conv_w = (const float*)d_in[4];    // (4,16,128,3,3)
    const float* conv_b = (const float*)d_in[5];    // (4,16)
    float* out = (float*)d_out;                     // (4,64,128,128)

    char* ws = (char*)d_ws;
    bf16*  Phi   = (bf16*) (ws + 0);            //  4,718,592 B
    bf16*  Plo   = (bf16*) (ws + 4718592);      //  4,718,592 B
    float* rnorm = (float*)(ws + 9437184);      //     16,384 B
    float* mi    = (float*)(ws + 9453568);      //     16,384 B
    float* S     = (float*)(ws + 9469952);      // 67,108,864 B (reused as V)
    bf16*  Abf   = (bf16*) (ws + 76578816);     // 33,554,432 B
    bf16*  Rt    = (bf16*) (ws + 110133248);    // 16,777,216 B
    float* yb    = (float*)(ws + 126910464);    //  8,388,608 B (end 135,299,072)
    float* V     = S;                           // S dead after softmax

    for (int b = 0; b < 4; ++b) {
        const float* x2b = x2 + (size_t)b * 64 * 4096;
        const float* x1b = x1 + (size_t)b * 128 * 16384;
        build_P_norm<<<4096, 64, 0, stream>>>(x2b, Phi, Plo, rnorm);
        build_mi<<<16, 256, 0, stream>>>(mask + (size_t)b * 16384, mi);
        gemm_score_mfma<<<dim3(32, 32), 256, 0, stream>>>(Phi, Plo, rnorm, S);
        softmax_mask<<<4096, 256, 0, stream>>>(S, mi, mask_all + (size_t)b * 4096, Abf);
        build_Rt<<<32768, 256, 0, stream>>>(x1b, Rt);
        gemm_deconv_mfma<<<dim3(16, 32), 256, 0, stream>>>(Abf, Rt, V);
        reconstruct<<<8192, 256, 0, stream>>>(V, yb);
        final_conv<<<dim3(64, 4), 256, 0, stream>>>(yb, conv_w, conv_b, out, b);
    }
}

// Round 3
// 991.639 us; speedup vs baseline: 5.5348x; 1.6148x over previous
//
#include <hip/hip_runtime.h>
#include <math.h>

typedef __bf16 bf16;
typedef __attribute__((ext_vector_type(8))) __bf16 bf16x8;
typedef __attribute__((ext_vector_type(4))) float f32x4;

#define LPOS 4096      // 64*64 positions / patches
#define KPAT 576       // 64ch * 3*3 patch
#define RPAT 2048      // 128ch * 4*4 raw patch

#define GLDS(g, l) __builtin_amdgcn_global_load_lds( \
    (const __attribute__((address_space(1))) void*)(g), \
    (__attribute__((address_space(3))) void*)(l), 16, 0, 0)

// ---------------------------------------------------------------------------
// Phi/Plo[pos][576] = split-bf16 of 3x3x64 patches of x2[b]; rnorm[pos]
__global__ __launch_bounds__(64) void build_P_norm(const float* __restrict__ x2b,
                                                   bf16* __restrict__ Phi,
                                                   bf16* __restrict__ Plo,
                                                   float* __restrict__ rnorm) {
    int pos = blockIdx.x;
    int u = pos >> 6, v = pos & 63;
    int tid = threadIdx.x;
    float ss = 0.f;
    for (int k = tid; k < KPAT; k += 64) {
        int c = k / 9, r9 = k % 9;
        int di = r9 / 3, dj = r9 % 3;
        int yy = u + di - 1, xx = v + dj - 1;
        float val = 0.f;
        if (yy >= 0 && yy < 64 && xx >= 0 && xx < 64)
            val = x2b[c * 4096 + yy * 64 + xx];
        bf16 hi = (bf16)val;
        Phi[pos * KPAT + k] = hi;
        Plo[pos * KPAT + k] = (bf16)(val - (float)hi);
        ss += val * val;
    }
#pragma unroll
    for (int off = 32; off; off >>= 1) ss += __shfl_xor(ss, off, 64);
    if (tid == 0) rnorm[pos] = 1.f / fmaxf(sqrtf(ss), 1e-4f);
}

// ---------------------------------------------------------------------------
__global__ __launch_bounds__(256) void build_mi(const float* __restrict__ maskb,
                                                float* __restrict__ mi) {
    int pos = blockIdx.x * 256 + threadIdx.x;
    if (pos >= LPOS) return;
    int pu = pos >> 6, pv = pos & 63;
    float s = 0.f;
    for (int t = 0; t < 4; ++t)
        for (int w = 0; w < 4; ++w) {
            int yy = 2 * pu - 1 + t, xx = 2 * pv - 1 + w;
            if (yy >= 0 && yy < 128 && xx >= 0 && xx < 128) s += maskb[yy * 128 + xx];
        }
    mi[pos] = (s == 0.f) ? 1.f : 0.f;
}

// ---------------------------------------------------------------------------
// S[m][n] = (Phi+Plo)[m] . (Phi+Plo)[n] * rnorm[n]  via 3-product split-bf16
__global__ __launch_bounds__(256) void gemm_score_mfma(const bf16* __restrict__ Phi,
                                                       const bf16* __restrict__ Plo,
                                                       const float* __restrict__ rnorm,
                                                       float* __restrict__ S) {
    __shared__ bf16 Ah[128 * 32], Al[128 * 32], Bh[128 * 32], Bl[128 * 32];
    int tid = threadIdx.x;
    int w = tid >> 6, lane = tid & 63;
    int wy = w >> 1, wx = w & 1;
    int m0 = blockIdx.y * 128, n0 = blockIdx.x * 128;
    f32x4 acc[4][4];
#pragma unroll
    for (int mt = 0; mt < 4; ++mt)
#pragma unroll
        for (int nt = 0; nt < 4; ++nt) acc[mt][nt] = (f32x4){0.f, 0.f, 0.f, 0.f};
    int srow = lane >> 2;           // 0..15
    int scol = (lane & 3) * 8;      // element offset within 32-wide K tile
    int q = (lane >> 4) * 8, r = lane & 15;
    for (int k0 = 0; k0 < KPAT; k0 += 32) {
#pragma unroll
        for (int i = 0; i < 2; ++i) {
            int row = w * 32 + i * 16 + srow;
            int ldso = row * 32 + scol;
            GLDS(Phi + (size_t)(m0 + row) * KPAT + k0 + scol, Ah + ldso);
            GLDS(Plo + (size_t)(m0 + row) * KPAT + k0 + scol, Al + ldso);
            GLDS(Phi + (size_t)(n0 + row) * KPAT + k0 + scol, Bh + ldso);
            GLDS(Plo + (size_t)(n0 + row) * KPAT + k0 + scol, Bl + ldso);
        }
        __syncthreads();
        bf16x8 vbh[4], vbl[4];
#pragma unroll
        for (int nt = 0; nt < 4; ++nt) {
            int rb = (wx * 64 + nt * 16 + r) * 32 + q;
            vbh[nt] = *(const bf16x8*)&Bh[rb];
            vbl[nt] = *(const bf16x8*)&Bl[rb];
        }
#pragma unroll
        for (int mt = 0; mt < 4; ++mt) {
            int ra = (wy * 64 + mt * 16 + r) * 32 + q;
            bf16x8 vah = *(const bf16x8*)&Ah[ra];
            bf16x8 vlo = *(const bf16x8*)&Al[ra];
#pragma unroll
            for (int nt = 0; nt < 4; ++nt) {
                acc[mt][nt] = __builtin_amdgcn_mfma_f32_16x16x32_bf16(vah, vbh[nt], acc[mt][nt], 0, 0, 0);
                acc[mt][nt] = __builtin_amdgcn_mfma_f32_16x16x32_bf16(vah, vbl[nt], acc[mt][nt], 0, 0, 0);
                acc[mt][nt] = __builtin_amdgcn_mfma_f32_16x16x32_bf16(vlo, vbh[nt], acc[mt][nt], 0, 0, 0);
            }
        }
        __syncthreads();
    }
    int qq = lane >> 4;
#pragma unroll
    for (int nt = 0; nt < 4; ++nt) {
        int col = n0 + wx * 64 + nt * 16 + r;
        float rn = rnorm[col];
#pragma unroll
        for (int mt = 0; mt < 4; ++mt)
#pragma unroll
            for (int ri = 0; ri < 4; ++ri) {
                int row = m0 + wy * 64 + mt * 16 + qq * 4 + ri;
                S[(size_t)row * LPOS + col] = acc[mt][nt][ri] * rn;
            }
    }
}

// ---------------------------------------------------------------------------
// Masked softmax over p per row; writes bf16 attention matrix Abf
__global__ __launch_bounds__(256) void softmax_mask(const float* __restrict__ S,
                                                    const float* __restrict__ mi,
                                                    const float* __restrict__ mab,
                                                    bf16* __restrict__ Abf) {
    int pos = blockIdx.x;
    int tid = threadIdx.x;
    float ma = mab[pos];
    float sc = 10.0f * ma;
    float v[16];
    float vmax = -1e30f;
#pragma unroll
    for (int i = 0; i < 16; ++i) {
        int p = tid + i * 256;
        float x = S[(size_t)pos * LPOS + p] * mi[p] * sc;
        v[i] = x;
        vmax = fmaxf(vmax, x);
    }
#pragma unroll
    for (int off = 32; off; off >>= 1) vmax = fmaxf(vmax, __shfl_xor(vmax, off, 64));
    __shared__ float sred[4];
    int wid = tid >> 6;
    if ((tid & 63) == 0) sred[wid] = vmax;
    __syncthreads();
    vmax = fmaxf(fmaxf(sred[0], sred[1]), fmaxf(sred[2], sred[3]));
    __syncthreads();
    float ssum = 0.f;
#pragma unroll
    for (int i = 0; i < 16; ++i) {
        float e = expf(v[i] - vmax);
        v[i] = e;
        ssum += e;
    }
#pragma unroll
    for (int off = 32; off; off >>= 1) ssum += __shfl_xor(ssum, off, 64);
    if ((tid & 63) == 0) sred[wid] = ssum;
    __syncthreads();
    float inv = 1.f / (sred[0] + sred[1] + sred[2] + sred[3]);
#pragma unroll
    for (int i = 0; i < 16; ++i) {
        int p = tid + i * 256;
        Abf[(size_t)pos * LPOS + p] = (bf16)(v[i] * inv * mi[p] * ma);
    }
}

// ---------------------------------------------------------------------------
// Rt[n][p] bf16, n = (t*4+s)*128 + c  (tap-major so reconstruct reads are
// c-contiguous), value = x1[b][c][2pu-1+t][2pv-1+s]
__global__ __launch_bounds__(256) void build_Rt(const float* __restrict__ x1b,
                                                bf16* __restrict__ Rt) {
    int idx = blockIdx.x * 256 + threadIdx.x;   // n*4096 + p
    int p = idx & 4095, n = idx >> 12;
    int pu = p >> 6, pv = p & 63;
    int t = (n >> 9) & 3, s = (n >> 7) & 3, c = n & 127;
    int yy = 2 * pu - 1 + t, xx = 2 * pv - 1 + s;
    float val = 0.f;
    if (yy >= 0 && yy < 128 && xx >= 0 && xx < 128)
        val = x1b[c * 16384 + yy * 128 + xx];
    Rt[idx] = (bf16)val;
}

// ---------------------------------------------------------------------------
// V[m][n] = sum_k A[m][k] * Bt[n][k]   M=4096, N=2048, K=4096 (bf16 MFMA)
__global__ __launch_bounds__(256) void gemm_deconv_mfma(const bf16* __restrict__ A,
                                                        const bf16* __restrict__ Bt,
                                                        float* __restrict__ V) {
    __shared__ bf16 As[128 * 32], Bs[128 * 32];
    int tid = threadIdx.x;
    int w = tid >> 6, lane = tid & 63;
    int wy = w >> 1, wx = w & 1;
    int m0 = blockIdx.y * 128, n0 = blockIdx.x * 128;
    f32x4 acc[4][4];
#pragma unroll
    for (int mt = 0; mt < 4; ++mt)
#pragma unroll
        for (int nt = 0; nt < 4; ++nt) acc[mt][nt] = (f32x4){0.f, 0.f, 0.f, 0.f};
    int srow = lane >> 2;
    int scol = (lane & 3) * 8;
    int q = (lane >> 4) * 8, r = lane & 15;
    for (int k0 = 0; k0 < LPOS; k0 += 32) {
#pragma unroll
        for (int i = 0; i < 2; ++i) {
            int row = w * 32 + i * 16 + srow;
            int ldso = row * 32 + scol;
            GLDS(A + (size_t)(m0 + row) * LPOS + k0 + scol, As + ldso);
            GLDS(Bt + (size_t)(n0 + row) * LPOS + k0 + scol, Bs + ldso);
        }
        __syncthreads();
        bf16x8 vb[4];
#pragma unroll
        for (int nt = 0; nt < 4; ++nt)
            vb[nt] = *(const bf16x8*)&Bs[(wx * 64 + nt * 16 + r) * 32 + q];
#pragma unroll
        for (int mt = 0; mt < 4; ++mt) {
            bf16x8 va = *(const bf16x8*)&As[(wy * 64 + mt * 16 + r) * 32 + q];
#pragma unroll
            for (int nt = 0; nt < 4; ++nt)
                acc[mt][nt] = __builtin_amdgcn_mfma_f32_16x16x32_bf16(va, vb[nt], acc[mt][nt], 0, 0, 0);
        }
        __syncthreads();
    }
    int qq = lane >> 4;
#pragma unroll
    for (int mt = 0; mt < 4; ++mt)
#pragma unroll
        for (int nt = 0; nt < 4; ++nt) {
            int col = n0 + wx * 64 + nt * 16 + r;
#pragma unroll
            for (int ri = 0; ri < 4; ++ri) {
                int row = m0 + wy * 64 + mt * 16 + qq * 4 + ri;
                V[(size_t)row * RPAT + col] = acc[mt][nt][ri];
            }
        }
}

// ---------------------------------------------------------------------------
// ybT[b][p][c] (bf16, channel-contiguous) = 0.25 * sum over valid taps of V
__global__ __launch_bounds__(256) void reconstruct(const float* __restrict__ V,
                                                   bf16* __restrict__ ybTb) {
    int idx = blockIdx.x * 256 + threadIdx.x;   // p*128 + c
    int c = idx & 127, p = idx >> 7;
    int xx = p & 127, yy = p >> 7;
    float sum = 0.f;
    int tby = (yy & 1) ? 0 : 1;
    int tbx = (xx & 1) ? 0 : 1;
#pragma unroll
    for (int dt = 0; dt < 2; ++dt) {
        int t = tby + 2 * dt;
        int u2 = yy + 1 - t;
        if (u2 < 0 || u2 >= 128) continue;
        int u = u2 >> 1;
#pragma unroll
        for (int ds = 0; ds < 2; ++ds) {
            int s = tbx + 2 * ds;
            int v2 = xx + 1 - s;
            if (v2 < 0 || v2 >= 128) continue;
            int v = v2 >> 1;
            sum += V[(size_t)(u * 64 + v) * RPAT + (t * 4 + s) * 128 + c];
        }
    }
    ybTb[idx] = (bf16)(0.25f * sum);
}

// ---------------------------------------------------------------------------
// Wt[g][tap][oc][c] bf16 from conv_w (4,16,128,3,3) fp32
__global__ __launch_bounds__(256) void prep_w(const float* __restrict__ cw,
                                              bf16* __restrict__ Wt) {
    int idx = blockIdx.x * 256 + threadIdx.x;
    if (idx >= 4 * 9 * 16 * 128) return;
    int g = idx / 18432, rem = idx % 18432;
    int tap = rem >> 11, oc = (rem >> 7) & 15, c = rem & 127;
    Wt[idx] = (bf16)cw[(((g * 16 + oc) * 128 + c) * 9) + tap];
}

// ---------------------------------------------------------------------------
// Tap-decomposed implicit-GEMM grouped dilated conv via MFMA.
// Block: 4 waves, covers 2 image rows (256 positions) for one (g, b).
// Wave: 64 positions x 16 oc, K = 9 taps x 128 channels.
__global__ __launch_bounds__(256) void final_conv_mfma(const bf16* __restrict__ ybT,
                                                       const bf16* __restrict__ Wt,
                                                       const float* __restrict__ cb,
                                                       float* __restrict__ out) {
    int b = blockIdx.z, g = blockIdx.y, rp = blockIdx.x;
    int tid = threadIdx.x, w = tid >> 6, lane = tid & 63;
    int y = rp * 2 + (w >> 1);
    int xbase = (w & 1) * 64;
    int r = 1 << g;                 // RATES = 1,2,4,8
    int m = lane & 15, q = lane >> 4;
    const bf16* yB = ybT + (size_t)b * 16384 * 128;
    const bf16* Wg = Wt + (size_t)g * 9 * 16 * 128;
    f32x4 acc[4];
#pragma unroll
    for (int mt = 0; mt < 4; ++mt) acc[mt] = (f32x4){0.f, 0.f, 0.f, 0.f};
#pragma unroll
    for (int tap = 0; tap < 9; ++tap) {
        int dy = (tap / 3 - 1) * r, dx = (tap % 3 - 1) * r;
        int yy = y + dy;
        bool rowok = (yy >= 0 && yy < 128);
        const bf16* wrow = Wg + (tap * 16 + m) * 128 + q * 8;
        const bf16* arow = yB + ((size_t)yy * 128) * 128 + q * 8;
#pragma unroll
        for (int ks = 0; ks < 4; ++ks) {
            bf16x8 bfrag = *(const bf16x8*)(wrow + ks * 32);
#pragma unroll
            for (int mt = 0; mt < 4; ++mt) {
                int xx = xbase + mt * 16 + m + dx;
                bf16x8 afrag = {};
                if (rowok && xx >= 0 && xx < 128)
                    afrag = *(const bf16x8*)(arow + (size_t)xx * 128 + ks * 32);
                acc[mt] = __builtin_amdgcn_mfma_f32_16x16x32_bf16(afrag, bfrag, acc[mt], 0, 0, 0);
            }
        }
    }
    float bias = cb[g * 16 + m];    // output col index (oc) == lane&15
    float* orow = out + ((size_t)(b * 64 + g * 16 + m)) * 16384 + (size_t)y * 128;
#pragma unroll
    for (int mt = 0; mt < 4; ++mt)
#pragma unroll
        for (int ri = 0; ri < 4; ++ri) {
            int x = xbase + mt * 16 + q * 4 + ri;
            orow[x] = fmaxf(acc[mt][ri] + bias, 0.f);
        }
}

// ---------------------------------------------------------------------------
extern "C" void kernel_launch(void* const* d_in, const int* in_sizes, int n_in,
                              void* d_out, int out_size, void* d_ws, size_t ws_size,
                              hipStream_t stream) {
    const float* x1 = (const float*)d_in[0];        // (4,128,128,128)
    const float* x2 = (const float*)d_in[1];        // (4,64,64,64)
    const float* mask = (const float*)d_in[2];      // (4,1,128,128)
    const float* mask_all = (const float*)d_in[3];  // (4,1,64,64)
    const float* conv_w = (const float*)d_in[4];    // (4,16,128,3,3)
    const float* conv_b = (const float*)d_in[5];    // (4,16)
    float* out = (float*)d_out;                     // (4,64,128,128)

    char* ws = (char*)d_ws;
    bf16*  Phi   = (bf16*) (ws + 0);            //  4,718,592 B
    bf16*  Plo   = (bf16*) (ws + 4718592);      //  4,718,592 B
    float* rnorm = (float*)(ws + 9437184);      //     16,384 B
    float* mi    = (float*)(ws + 9453568);      //     16,384 B
    float* S     = (float*)(ws + 9469952);      // 67,108,864 B (reused as V)
    bf16*  Abf   = (bf16*) (ws + 76578816);     // 33,554,432 B
    bf16*  Rt    = (bf16*) (ws + 110133248);    // 16,777,216 B
    bf16*  ybT   = (bf16*) (ws + 126910464);    // 16,777,216 B (all 4 batches)
    bf16*  Wt    = (bf16*) (ws + 143687680);    //    147,456 B (end 143,835,136)
    float* V     = S;                           // S dead after softmax

    prep_w<<<288, 256, 0, stream>>>(conv_w, Wt);
    for (int b = 0; b < 4; ++b) {
        const float* x2b = x2 + (size_t)b * 64 * 4096;
        const float* x1b = x1 + (size_t)b * 128 * 16384;
        build_P_norm<<<4096, 64, 0, stream>>>(x2b, Phi, Plo, rnorm);
        build_mi<<<16, 256, 0, stream>>>(mask + (size_t)b * 16384, mi);
        gemm_score_mfma<<<dim3(32, 32), 256, 0, stream>>>(Phi, Plo, rnorm, S);
        softmax_mask<<<4096, 256, 0, stream>>>(S, mi, mask_all + (size_t)b * 4096, Abf);
        build_Rt<<<32768, 256, 0, stream>>>(x1b, Rt);
        gemm_deconv_mfma<<<dim3(16, 32), 256, 0, stream>>>(Abf, Rt, V);
        reconstruct<<<8192, 256, 0, stream>>>(V, ybT + (size_t)b * 16384 * 128);
    }
    final_conv_mfma<<<dim3(64, 4, 4), 256, 0, stream>>>(ybT, Wt, conv_b, out);
}

// Round 4
// 947.942 us; speedup vs baseline: 5.7899x; 1.0461x over previous
//
#include <hip/hip_runtime.h>
#include <math.h>

typedef _Float16 f16;
typedef __attribute__((ext_vector_type(8))) _Float16 f16x8;
typedef __attribute__((ext_vector_type(4))) float f32x4;

#define LPOS 4096      // 64*64 positions / patches
#define KPAT 576       // 64ch * 3*3 patch
#define RPAT 2048      // 128ch * 4*4 raw patch

#define GLDS(g, l) __builtin_amdgcn_global_load_lds( \
    (const __attribute__((address_space(1))) void*)(g), \
    (__attribute__((address_space(3))) void*)(l), 16, 0, 0)

// ---------------------------------------------------------------------------
// Ph[pos][576] = fp16 3x3x64 patches of x2[b] (zero pad 1); rnorm[pos]
__global__ __launch_bounds__(64) void build_P_norm(const float* __restrict__ x2b,
                                                   f16* __restrict__ Ph,
                                                   float* __restrict__ rnorm) {
    int pos = blockIdx.x;
    int u = pos >> 6, v = pos & 63;
    int tid = threadIdx.x;
    float ss = 0.f;
    for (int k = tid; k < KPAT; k += 64) {
        int c = k / 9, r9 = k % 9;
        int di = r9 / 3, dj = r9 % 3;
        int yy = u + di - 1, xx = v + dj - 1;
        float val = 0.f;
        if (yy >= 0 && yy < 64 && xx >= 0 && xx < 64)
            val = x2b[c * 4096 + yy * 64 + xx];
        Ph[pos * KPAT + k] = (f16)val;
        ss += val * val;
    }
#pragma unroll
    for (int off = 32; off; off >>= 1) ss += __shfl_xor(ss, off, 64);
    if (tid == 0) rnorm[pos] = 1.f / fmaxf(sqrtf(ss), 1e-4f);
}

// ---------------------------------------------------------------------------
// Single-block: keep flags (4x4 stride-2 mask patch all zero) -> compacted
// index list cidx[0..nkeep), zero-padded to 4352; nk = {nkeep, kpad32}
__global__ __launch_bounds__(256) void compact_mask(const float* __restrict__ maskb,
                                                    int* __restrict__ cidx,
                                                    int* __restrict__ nk) {
    int tid = threadIdx.x;
    int keep[16];
    int cnt = 0;
#pragma unroll
    for (int e = 0; e < 16; ++e) {
        int pos = tid * 16 + e;
        int pu = pos >> 6, pv = pos & 63;
        float s = 0.f;
        for (int t = 0; t < 4; ++t)
            for (int w = 0; w < 4; ++w) {
                int yy = 2 * pu - 1 + t, xx = 2 * pv - 1 + w;
                if (yy >= 0 && yy < 128 && xx >= 0 && xx < 128)
                    s += maskb[yy * 128 + xx];
            }
        keep[e] = (s == 0.f) ? 1 : 0;
        cnt += keep[e];
    }
    __shared__ int ps[256];
    ps[tid] = cnt;
    __syncthreads();
    for (int off = 1; off < 256; off <<= 1) {
        int v = (tid >= off) ? ps[tid - off] : 0;
        __syncthreads();
        ps[tid] += v;
        __syncthreads();
    }
    int total = ps[255];
    int base = ps[tid] - cnt;   // exclusive prefix
#pragma unroll
    for (int e = 0; e < 16; ++e)
        if (keep[e]) cidx[base++] = tid * 16 + e;
    for (int i = total + tid; i < 4352; i += 256) cidx[i] = 0;
    if (tid == 0) { nk[0] = total; nk[1] = (total + 31) & ~31; }
}

// ---------------------------------------------------------------------------
// S[m][j] = Ph[m] . Ph[cidx[j]] * rnorm[cidx[j]]   (fp16 MFMA, gathered B)
__global__ __launch_bounds__(256) void gemm_score_mfma(const f16* __restrict__ Ph,
                                                       const int* __restrict__ cidx,
                                                       const float* __restrict__ rnorm,
                                                       const int* __restrict__ nk,
                                                       float* __restrict__ S) {
    int n0 = blockIdx.x * 128;
    if (n0 >= nk[0]) return;    // fully-masked column tile
    __shared__ f16 Ash[128 * 32], Bsh[128 * 32];
    int tid = threadIdx.x;
    int w = tid >> 6, lane = tid & 63;
    int wy = w >> 1, wx = w & 1;
    int m0 = blockIdx.y * 128;
    f32x4 acc[4][4];
#pragma unroll
    for (int mt = 0; mt < 4; ++mt)
#pragma unroll
        for (int nt = 0; nt < 4; ++nt) acc[mt][nt] = (f32x4){0.f, 0.f, 0.f, 0.f};
    int srow = lane >> 2;
    int scol = (lane & 3) * 8;
    int q = (lane >> 4) * 8, r = lane & 15;
    const f16* Asrc[2]; const f16* Bsrc[2]; int ldso[2];
#pragma unroll
    for (int i = 0; i < 2; ++i) {
        int row = w * 32 + i * 16 + srow;
        ldso[i] = row * 32 + scol;
        Asrc[i] = Ph + (size_t)(m0 + row) * KPAT + scol;
        Bsrc[i] = Ph + (size_t)cidx[n0 + row] * KPAT + scol;
    }
    for (int k0 = 0; k0 < KPAT; k0 += 32) {
#pragma unroll
        for (int i = 0; i < 2; ++i) {
            GLDS(Asrc[i] + k0, Ash + ldso[i]);
            GLDS(Bsrc[i] + k0, Bsh + ldso[i]);
        }
        __syncthreads();
        f16x8 vb[4];
#pragma unroll
        for (int nt = 0; nt < 4; ++nt)
            vb[nt] = *(const f16x8*)&Bsh[(wx * 64 + nt * 16 + r) * 32 + q];
#pragma unroll
        for (int mt = 0; mt < 4; ++mt) {
            f16x8 va = *(const f16x8*)&Ash[(wy * 64 + mt * 16 + r) * 32 + q];
#pragma unroll
            for (int nt = 0; nt < 4; ++nt)
                acc[mt][nt] = __builtin_amdgcn_mfma_f32_16x16x32_f16(va, vb[nt], acc[mt][nt], 0, 0, 0);
        }
        __syncthreads();
    }
    int qq = lane >> 4;
#pragma unroll
    for (int nt = 0; nt < 4; ++nt) {
        int col = n0 + wx * 64 + nt * 16 + r;
        float rn = rnorm[cidx[col]];
#pragma unroll
        for (int mt = 0; mt < 4; ++mt)
#pragma unroll
            for (int ri = 0; ri < 4; ++ri) {
                int row = m0 + wy * 64 + mt * 16 + qq * 4 + ri;
                S[(size_t)row * LPOS + col] = acc[mt][nt][ri] * rn;
            }
    }
}

// ---------------------------------------------------------------------------
// Masked softmax over compacted columns; masked entries contribute
// Nmasked * exp(-vmax) to the denominator (their logit is exactly 0).
__global__ __launch_bounds__(256) void softmax_mask(const float* __restrict__ S,
                                                    const int* __restrict__ nk,
                                                    const float* __restrict__ mab,
                                                    f16* __restrict__ Ah) {
    int pos = blockIdx.x;
    int tid = threadIdx.x;
    int nkeep = nk[0], kpad = nk[1];
    float ma = mab[pos];
    float sc = 10.0f * ma;
    float v[16];
    float vmax = (nkeep < LPOS) ? 0.f : -3.0e38f;
#pragma unroll
    for (int i = 0; i < 16; ++i) {
        int j = tid + i * 256;
        float x = (j < nkeep) ? S[(size_t)pos * LPOS + j] * sc : -3.0e38f;
        v[i] = x;
        vmax = fmaxf(vmax, x);
    }
#pragma unroll
    for (int off = 32; off; off >>= 1) vmax = fmaxf(vmax, __shfl_xor(vmax, off, 64));
    __shared__ float sred[4];
    int wid = tid >> 6;
    if ((tid & 63) == 0) sred[wid] = vmax;
    __syncthreads();
    vmax = fmaxf(fmaxf(sred[0], sred[1]), fmaxf(sred[2], sred[3]));
    __syncthreads();
    float ssum = 0.f;
#pragma unroll
    for (int i = 0; i < 16; ++i) {
        float e = (v[i] > -1.0e37f) ? __expf(v[i] - vmax) : 0.f;
        v[i] = e;
        ssum += e;
    }
#pragma unroll
    for (int off = 32; off; off >>= 1) ssum += __shfl_xor(ssum, off, 64);
    if ((tid & 63) == 0) sred[wid] = ssum;
    __syncthreads();
    float total = sred[0] + sred[1] + sred[2] + sred[3]
                + (float)(LPOS - nkeep) * __expf(-vmax);
    float inv = 1.f / total;
#pragma unroll
    for (int i = 0; i < 16; ++i) {
        int j = tid + i * 256;
        if (j < nkeep)      Ah[(size_t)pos * LPOS + j] = (f16)(v[i] * inv * ma);
        else if (j < kpad)  Ah[(size_t)pos * LPOS + j] = (f16)0.f;
    }
}

// ---------------------------------------------------------------------------
// Rt[n][j] fp16, n = (t*4+s)*128 + c, patch p = cidx[j] (compacted gather)
__global__ __launch_bounds__(256) void build_Rt(const float* __restrict__ x1b,
                                                const int* __restrict__ cidx,
                                                const int* __restrict__ nk,
                                                f16* __restrict__ Rt) {
    int idx = blockIdx.x * 256 + threadIdx.x;   // n*4096 + j
    int j = idx & 4095, n = idx >> 12;
    if (j >= nk[1]) return;
    int p = cidx[j];
    int pu = p >> 6, pv = p & 63;
    int t = (n >> 9) & 3, s = (n >> 7) & 3, c = n & 127;
    int yy = 2 * pu - 1 + t, xx = 2 * pv - 1 + s;
    float val = 0.f;
    if (yy >= 0 && yy < 128 && xx >= 0 && xx < 128)
        val = x1b[c * 16384 + yy * 128 + xx];
    Rt[idx] = (f16)val;
}

// ---------------------------------------------------------------------------
// V[m][n] = sum_{k<kpad} A[m][k] * Bt[n][k]   (fp16 MFMA, dynamic K)
__global__ __launch_bounds__(256) void gemm_deconv_mfma(const f16* __restrict__ A,
                                                        const f16* __restrict__ Bt,
                                                        const int* __restrict__ nk,
                                                        float* __restrict__ V) {
    __shared__ f16 Ash[128 * 32], Bsh[128 * 32];
    int kpad = nk[1];
    int tid = threadIdx.x;
    int w = tid >> 6, lane = tid & 63;
    int wy = w >> 1, wx = w & 1;
    int m0 = blockIdx.y * 128, n0 = blockIdx.x * 128;
    f32x4 acc[4][4];
#pragma unroll
    for (int mt = 0; mt < 4; ++mt)
#pragma unroll
        for (int nt = 0; nt < 4; ++nt) acc[mt][nt] = (f32x4){0.f, 0.f, 0.f, 0.f};
    int srow = lane >> 2;
    int scol = (lane & 3) * 8;
    int q = (lane >> 4) * 8, r = lane & 15;
    for (int k0 = 0; k0 < kpad; k0 += 32) {
#pragma unroll
        for (int i = 0; i < 2; ++i) {
            int row = w * 32 + i * 16 + srow;
            int ldso = row * 32 + scol;
            GLDS(A + (size_t)(m0 + row) * LPOS + k0 + scol, Ash + ldso);
            GLDS(Bt + (size_t)(n0 + row) * LPOS + k0 + scol, Bsh + ldso);
        }
        __syncthreads();
        f16x8 vb[4];
#pragma unroll
        for (int nt = 0; nt < 4; ++nt)
            vb[nt] = *(const f16x8*)&Bsh[(wx * 64 + nt * 16 + r) * 32 + q];
#pragma unroll
        for (int mt = 0; mt < 4; ++mt) {
            f16x8 va = *(const f16x8*)&Ash[(wy * 64 + mt * 16 + r) * 32 + q];
#pragma unroll
            for (int nt = 0; nt < 4; ++nt)
                acc[mt][nt] = __builtin_amdgcn_mfma_f32_16x16x32_f16(va, vb[nt], acc[mt][nt], 0, 0, 0);
        }
        __syncthreads();
    }
    int qq = lane >> 4;
#pragma unroll
    for (int mt = 0; mt < 4; ++mt)
#pragma unroll
        for (int nt = 0; nt < 4; ++nt) {
            int col = n0 + wx * 64 + nt * 16 + r;
#pragma unroll
            for (int ri = 0; ri < 4; ++ri) {
                int row = m0 + wy * 64 + mt * 16 + qq * 4 + ri;
                V[(size_t)row * RPAT + col] = acc[mt][nt][ri];
            }
        }
}

// ---------------------------------------------------------------------------
// ybT[b][p][c] (fp16, channel-contiguous) = 0.25 * sum over valid taps of V
__global__ __launch_bounds__(256) void reconstruct(const float* __restrict__ V,
                                                   f16* __restrict__ ybTb) {
    int idx = blockIdx.x * 256 + threadIdx.x;   // p*128 + c
    int c = idx & 127, p = idx >> 7;
    int xx = p & 127, yy = p >> 7;
    float sum = 0.f;
    int tby = (yy & 1) ? 0 : 1;
    int tbx = (xx & 1) ? 0 : 1;
#pragma unroll
    for (int dt = 0; dt < 2; ++dt) {
        int t = tby + 2 * dt;
        int u2 = yy + 1 - t;
        if (u2 < 0 || u2 >= 128) continue;
        int u = u2 >> 1;
#pragma unroll
        for (int ds = 0; ds < 2; ++ds) {
            int s = tbx + 2 * ds;
            int v2 = xx + 1 - s;
            if (v2 < 0 || v2 >= 128) continue;
            int v = v2 >> 1;
            sum += V[(size_t)(u * 64 + v) * RPAT + (t * 4 + s) * 128 + c];
        }
    }
    ybTb[idx] = (f16)(0.25f * sum);
}

// ---------------------------------------------------------------------------
// Wt[g][tap][oc][c] fp16 from conv_w (4,16,128,3,3) fp32
__global__ __launch_bounds__(256) void prep_w(const float* __restrict__ cw,
                                              f16* __restrict__ Wt) {
    int idx = blockIdx.x * 256 + threadIdx.x;
    if (idx >= 4 * 9 * 16 * 128) return;
    int g = idx / 18432, rem = idx % 18432;
    int tap = rem >> 11, oc = (rem >> 7) & 15, c = rem & 127;
    Wt[idx] = (f16)cw[(((g * 16 + oc) * 128 + c) * 9) + tap];
}

// ---------------------------------------------------------------------------
// Tap-decomposed implicit-GEMM grouped dilated conv via MFMA (fp16).
__global__ __launch_bounds__(256) void final_conv_mfma(const f16* __restrict__ ybT,
                                                       const f16* __restrict__ Wt,
                                                       const float* __restrict__ cb,
                                                       float* __restrict__ out) {
    int b = blockIdx.z, g = blockIdx.y, rp = blockIdx.x;
    int tid = threadIdx.x, w = tid >> 6, lane = tid & 63;
    int y = rp * 2 + (w >> 1);
    int xbase = (w & 1) * 64;
    int r = 1 << g;                 // RATES = 1,2,4,8
    int m = lane & 15, q = lane >> 4;
    const f16* yB = ybT + (size_t)b * 16384 * 128;
    const f16* Wg = Wt + (size_t)g * 9 * 16 * 128;
    f32x4 acc[4];
#pragma unroll
    for (int mt = 0; mt < 4; ++mt) acc[mt] = (f32x4){0.f, 0.f, 0.f, 0.f};
#pragma unroll
    for (int tap = 0; tap < 9; ++tap) {
        int dy = (tap / 3 - 1) * r, dx = (tap % 3 - 1) * r;
        int yy = y + dy;
        bool rowok = (yy >= 0 && yy < 128);
        const f16* wrow = Wg + (tap * 16 + m) * 128 + q * 8;
        const f16* arow = yB + ((size_t)yy * 128) * 128 + q * 8;
#pragma unroll
        for (int ks = 0; ks < 4; ++ks) {
            f16x8 bfrag = *(const f16x8*)(wrow + ks * 32);
#pragma unroll
            for (int mt = 0; mt < 4; ++mt) {
                int xx = xbase + mt * 16 + m + dx;
                f16x8 afrag = {};
                if (rowok && xx >= 0 && xx < 128)
                    afrag = *(const f16x8*)(arow + (size_t)xx * 128 + ks * 32);
                acc[mt] = __builtin_amdgcn_mfma_f32_16x16x32_f16(afrag, bfrag, acc[mt], 0, 0, 0);
            }
        }
    }
    float bias = cb[g * 16 + m];
    float* orow = out + ((size_t)(b * 64 + g * 16 + m)) * 16384 + (size_t)y * 128;
#pragma unroll
    for (int mt = 0; mt < 4; ++mt)
#pragma unroll
        for (int ri = 0; ri < 4; ++ri) {
            int x = xbase + mt * 16 + q * 4 + ri;
            orow[x] = fmaxf(acc[mt][ri] + bias, 0.f);
        }
}

// ---------------------------------------------------------------------------
extern "C" void kernel_launch(void* const* d_in, const int* in_sizes, int n_in,
                              void* d_out, int out_size, void* d_ws, size_t ws_size,
                              hipStream_t stream) {
    const float* x1 = (const float*)d_in[0];        // (4,128,128,128)
    const float* x2 = (const float*)d_in[1];        // (4,64,64,64)
    const float* mask = (const float*)d_in[2];      // (4,1,128,128)
    const float* mask_all = (const float*)d_in[3];  // (4,1,64,64)
    const float* conv_w = (const float*)d_in[4];    // (4,16,128,3,3)
    const float* conv_b = (const float*)d_in[5];    // (4,16)
    float* out = (float*)d_out;                     // (4,64,128,128)

    char* ws = (char*)d_ws;
    f16*   Ph    = (f16*)  (ws + 0);            //  4,718,592 B
    float* rnorm = (float*)(ws + 4718592);      //     16,384 B
    int*   cidx  = (int*)  (ws + 4734976);      //     17,408 B
    int*   nk    = (int*)  (ws + 4752384);      //        256 B
    float* S     = (float*)(ws + 9469952);      // 67,108,864 B (reused as V)
    f16*   Ah    = (f16*)  (ws + 76578816);     // 33,554,432 B
    f16*   Rt    = (f16*)  (ws + 110133248);    // 16,777,216 B
    f16*   ybT   = (f16*)  (ws + 126910464);    // 16,777,216 B (all 4 batches)
    f16*   Wt    = (f16*)  (ws + 143687680);    //     73,728 B (end 143,761,408)
    float* V     = S;                           // S dead after softmax

    prep_w<<<288, 256, 0, stream>>>(conv_w, Wt);
    for (int b = 0; b < 4; ++b) {
        const float* x2b = x2 + (size_t)b * 64 * 4096;
        const float* x1b = x1 + (size_t)b * 128 * 16384;
        build_P_norm<<<4096, 64, 0, stream>>>(x2b, Ph, rnorm);
        compact_mask<<<1, 256, 0, stream>>>(mask + (size_t)b * 16384, cidx, nk);
        gemm_score_mfma<<<dim3(32, 32), 256, 0, stream>>>(Ph, cidx, rnorm, nk, S);
        softmax_mask<<<4096, 256, 0, stream>>>(S, nk, mask_all + (size_t)b * 4096, Ah);
        build_Rt<<<32768, 256, 0, stream>>>(x1b, cidx, nk, Rt);
        gemm_deconv_mfma<<<dim3(16, 32), 256, 0, stream>>>(Ah, Rt, nk, V);
        reconstruct<<<8192, 256, 0, stream>>>(V, ybT + (size_t)b * 16384 * 128);
    }
    final_conv_mfma<<<dim3(64, 4, 4), 256, 0, stream>>>(ybT, Wt, conv_b, out);
}

// Round 5
// 809.901 us; speedup vs baseline: 6.7768x; 1.1704x over previous
//
#include <hip/hip_runtime.h>
#include <math.h>

typedef _Float16 f16;
typedef __attribute__((ext_vector_type(8))) _Float16 f16x8;
typedef __attribute__((ext_vector_type(4))) float f32x4;

#define LPOS 4096      // 64*64 positions / patches
#define KPAT 576       // 64ch * 3*3 patch
#define RPAT 2048      // 128ch * 4*4 raw patch

#define GLDS(g, l) __builtin_amdgcn_global_load_lds( \
    (const __attribute__((address_space(1))) void*)(g), \
    (__attribute__((address_space(3))) void*)(l), 16, 0, 0)

// ---------------------------------------------------------------------------
// Ph[pos][576] = fp16 3x3x64 patches of x2[b] (zero pad 1); rnorm[pos]
__global__ __launch_bounds__(64) void build_P_norm(const float* __restrict__ x2b,
                                                   f16* __restrict__ Ph,
                                                   float* __restrict__ rnorm) {
    int pos = blockIdx.x;
    int u = pos >> 6, v = pos & 63;
    int tid = threadIdx.x;
    float ss = 0.f;
    for (int k = tid; k < KPAT; k += 64) {
        int c = k / 9, r9 = k % 9;
        int di = r9 / 3, dj = r9 % 3;
        int yy = u + di - 1, xx = v + dj - 1;
        float val = 0.f;
        if (yy >= 0 && yy < 64 && xx >= 0 && xx < 64)
            val = x2b[c * 4096 + yy * 64 + xx];
        Ph[pos * KPAT + k] = (f16)val;
        ss += val * val;
    }
#pragma unroll
    for (int off = 32; off; off >>= 1) ss += __shfl_xor(ss, off, 64);
    if (tid == 0) rnorm[pos] = 1.f / fmaxf(sqrtf(ss), 1e-4f);
}

// ---------------------------------------------------------------------------
// All 4 batches in one launch: block b compacts mask[b] -> cidx[b], nk[b]
__global__ __launch_bounds__(256) void compact_mask_all(const float* __restrict__ mask,
                                                        int* __restrict__ cidx_all,
                                                        int* __restrict__ nk_all) {
    int b = blockIdx.x;
    const float* maskb = mask + (size_t)b * 16384;
    int* cidx = cidx_all + b * 4352;
    int* nk = nk_all + b * 2;
    int tid = threadIdx.x;
    int keep[16];
    int cnt = 0;
#pragma unroll
    for (int e = 0; e < 16; ++e) {
        int pos = tid * 16 + e;
        int pu = pos >> 6, pv = pos & 63;
        float s = 0.f;
        for (int t = 0; t < 4; ++t)
            for (int w = 0; w < 4; ++w) {
                int yy = 2 * pu - 1 + t, xx = 2 * pv - 1 + w;
                if (yy >= 0 && yy < 128 && xx >= 0 && xx < 128)
                    s += maskb[yy * 128 + xx];
            }
        keep[e] = (s == 0.f) ? 1 : 0;
        cnt += keep[e];
    }
    __shared__ int ps[256];
    ps[tid] = cnt;
    __syncthreads();
    for (int off = 1; off < 256; off <<= 1) {
        int v = (tid >= off) ? ps[tid - off] : 0;
        __syncthreads();
        ps[tid] += v;
        __syncthreads();
    }
    int total = ps[255];
    int base = ps[tid] - cnt;   // exclusive prefix
#pragma unroll
    for (int e = 0; e < 16; ++e)
        if (keep[e]) cidx[base++] = tid * 16 + e;
    for (int i = total + tid; i < 4352; i += 256) cidx[i] = 0;
    if (tid == 0) { nk[0] = total; nk[1] = (total + 31) & ~31; }
}

// ---------------------------------------------------------------------------
// S[m][j] = Ph[m] . Ph[cidx[j]] * rnorm[cidx[j]]   (fp16 MFMA, gathered B)
__global__ __launch_bounds__(256) void gemm_score_mfma(const f16* __restrict__ Ph,
                                                       const int* __restrict__ cidx,
                                                       const float* __restrict__ rnorm,
                                                       const int* __restrict__ nk,
                                                       float* __restrict__ S) {
    int n0 = blockIdx.x * 128;
    if (n0 >= nk[0]) return;    // fully-masked column tile
    __shared__ f16 Ash[128 * 32], Bsh[128 * 32];
    int tid = threadIdx.x;
    int w = tid >> 6, lane = tid & 63;
    int wy = w >> 1, wx = w & 1;
    int m0 = blockIdx.y * 128;
    f32x4 acc[4][4];
#pragma unroll
    for (int mt = 0; mt < 4; ++mt)
#pragma unroll
        for (int nt = 0; nt < 4; ++nt) acc[mt][nt] = (f32x4){0.f, 0.f, 0.f, 0.f};
    int srow = lane >> 2;
    int scol = (lane & 3) * 8;
    int q = (lane >> 4) * 8, r = lane & 15;
    const f16* Asrc[2]; const f16* Bsrc[2]; int ldso[2];
#pragma unroll
    for (int i = 0; i < 2; ++i) {
        int row = w * 32 + i * 16 + srow;
        ldso[i] = row * 32 + scol;
        Asrc[i] = Ph + (size_t)(m0 + row) * KPAT + scol;
        Bsrc[i] = Ph + (size_t)cidx[n0 + row] * KPAT + scol;
    }
    for (int k0 = 0; k0 < KPAT; k0 += 32) {
#pragma unroll
        for (int i = 0; i < 2; ++i) {
            GLDS(Asrc[i] + k0, Ash + ldso[i]);
            GLDS(Bsrc[i] + k0, Bsh + ldso[i]);
        }
        __syncthreads();
        f16x8 vb[4];
#pragma unroll
        for (int nt = 0; nt < 4; ++nt)
            vb[nt] = *(const f16x8*)&Bsh[(wx * 64 + nt * 16 + r) * 32 + q];
#pragma unroll
        for (int mt = 0; mt < 4; ++mt) {
            f16x8 va = *(const f16x8*)&Ash[(wy * 64 + mt * 16 + r) * 32 + q];
#pragma unroll
            for (int nt = 0; nt < 4; ++nt)
                acc[mt][nt] = __builtin_amdgcn_mfma_f32_16x16x32_f16(va, vb[nt], acc[mt][nt], 0, 0, 0);
        }
        __syncthreads();
    }
    int qq = lane >> 4;
#pragma unroll
    for (int nt = 0; nt < 4; ++nt) {
        int col = n0 + wx * 64 + nt * 16 + r;
        float rn = rnorm[cidx[col]];
#pragma unroll
        for (int mt = 0; mt < 4; ++mt)
#pragma unroll
            for (int ri = 0; ri < 4; ++ri) {
                int row = m0 + wy * 64 + mt * 16 + qq * 4 + ri;
                S[(size_t)row * LPOS + col] = acc[mt][nt][ri] * rn;
            }
    }
}

// ---------------------------------------------------------------------------
// Masked softmax over compacted columns; masked entries contribute
// Nmasked * exp(-vmax) to the denominator (their logit is exactly 0).
__global__ __launch_bounds__(256) void softmax_mask(const float* __restrict__ S,
                                                    const int* __restrict__ nk,
                                                    const float* __restrict__ mab,
                                                    f16* __restrict__ Ah) {
    int pos = blockIdx.x;
    int tid = threadIdx.x;
    int nkeep = nk[0], kpad = nk[1];
    float ma = mab[pos];
    float sc = 10.0f * ma;
    float v[16];
    float vmax = (nkeep < LPOS) ? 0.f : -3.0e38f;
#pragma unroll
    for (int i = 0; i < 16; ++i) {
        int j = tid + i * 256;
        float x = (j < nkeep) ? S[(size_t)pos * LPOS + j] * sc : -3.0e38f;
        v[i] = x;
        vmax = fmaxf(vmax, x);
    }
#pragma unroll
    for (int off = 32; off; off >>= 1) vmax = fmaxf(vmax, __shfl_xor(vmax, off, 64));
    __shared__ float sred[4];
    int wid = tid >> 6;
    if ((tid & 63) == 0) sred[wid] = vmax;
    __syncthreads();
    vmax = fmaxf(fmaxf(sred[0], sred[1]), fmaxf(sred[2], sred[3]));
    __syncthreads();
    float ssum = 0.f;
#pragma unroll
    for (int i = 0; i < 16; ++i) {
        float e = (v[i] > -1.0e37f) ? __expf(v[i] - vmax) : 0.f;
        v[i] = e;
        ssum += e;
    }
#pragma unroll
    for (int off = 32; off; off >>= 1) ssum += __shfl_xor(ssum, off, 64);
    if ((tid & 63) == 0) sred[wid] = ssum;
    __syncthreads();
    float total = sred[0] + sred[1] + sred[2] + sred[3]
                + (float)(LPOS - nkeep) * __expf(-vmax);
    float inv = 1.f / total;
#pragma unroll
    for (int i = 0; i < 16; ++i) {
        int j = tid + i * 256;
        if (j < nkeep)      Ah[(size_t)pos * LPOS + j] = (f16)(v[i] * inv * ma);
        else if (j < kpad)  Ah[(size_t)pos * LPOS + j] = (f16)0.f;
    }
}

// ---------------------------------------------------------------------------
// Rt[n][j] fp16, n = (t*4+s)*128 + c, patch p = cidx[j] (compacted gather)
__global__ __launch_bounds__(256) void build_Rt(const float* __restrict__ x1b,
                                                const int* __restrict__ cidx,
                                                const int* __restrict__ nk,
                                                f16* __restrict__ Rt) {
    int idx = blockIdx.x * 256 + threadIdx.x;   // n*4096 + j
    int j = idx & 4095, n = idx >> 12;
    if (j >= nk[1]) return;
    int p = cidx[j];
    int pu = p >> 6, pv = p & 63;
    int t = (n >> 9) & 3, s = (n >> 7) & 3, c = n & 127;
    int yy = 2 * pu - 1 + t, xx = 2 * pv - 1 + s;
    float val = 0.f;
    if (yy >= 0 && yy < 128 && xx >= 0 && xx < 128)
        val = x1b[c * 16384 + yy * 128 + xx];
    Rt[idx] = (f16)val;
}

// ---------------------------------------------------------------------------
// V[m][n] = sum_{k<kpad} A[m][k] * Bt[n][k]   (fp16 MFMA, dynamic K, fp16 out)
__global__ __launch_bounds__(256) void gemm_deconv_mfma(const f16* __restrict__ A,
                                                        const f16* __restrict__ Bt,
                                                        const int* __restrict__ nk,
                                                        f16* __restrict__ V) {
    __shared__ f16 Ash[128 * 32], Bsh[128 * 32];
    int kpad = nk[1];
    int tid = threadIdx.x;
    int w = tid >> 6, lane = tid & 63;
    int wy = w >> 1, wx = w & 1;
    int m0 = blockIdx.y * 128, n0 = blockIdx.x * 128;
    f32x4 acc[4][4];
#pragma unroll
    for (int mt = 0; mt < 4; ++mt)
#pragma unroll
        for (int nt = 0; nt < 4; ++nt) acc[mt][nt] = (f32x4){0.f, 0.f, 0.f, 0.f};
    int srow = lane >> 2;
    int scol = (lane & 3) * 8;
    int q = (lane >> 4) * 8, r = lane & 15;
    for (int k0 = 0; k0 < kpad; k0 += 32) {
#pragma unroll
        for (int i = 0; i < 2; ++i) {
            int row = w * 32 + i * 16 + srow;
            int ldso = row * 32 + scol;
            GLDS(A + (size_t)(m0 + row) * LPOS + k0 + scol, Ash + ldso);
            GLDS(Bt + (size_t)(n0 + row) * LPOS + k0 + scol, Bsh + ldso);
        }
        __syncthreads();
        f16x8 vb[4];
#pragma unroll
        for (int nt = 0; nt < 4; ++nt)
            vb[nt] = *(const f16x8*)&Bsh[(wx * 64 + nt * 16 + r) * 32 + q];
#pragma unroll
        for (int mt = 0; mt < 4; ++mt) {
            f16x8 va = *(const f16x8*)&Ash[(wy * 64 + mt * 16 + r) * 32 + q];
#pragma unroll
            for (int nt = 0; nt < 4; ++nt)
                acc[mt][nt] = __builtin_amdgcn_mfma_f32_16x16x32_f16(va, vb[nt], acc[mt][nt], 0, 0, 0);
        }
        __syncthreads();
    }
    int qq = lane >> 4;
#pragma unroll
    for (int mt = 0; mt < 4; ++mt)
#pragma unroll
        for (int nt = 0; nt < 4; ++nt) {
            int col = n0 + wx * 64 + nt * 16 + r;
#pragma unroll
            for (int ri = 0; ri < 4; ++ri) {
                int row = m0 + wy * 64 + mt * 16 + qq * 4 + ri;
                V[(size_t)row * RPAT + col] = (f16)acc[mt][nt][ri];
            }
        }
}

// ---------------------------------------------------------------------------
// ybT[b][p][c] (fp16, channel-contiguous) = 0.25 * sum over valid taps of V
__global__ __launch_bounds__(256) void reconstruct(const f16* __restrict__ V,
                                                   f16* __restrict__ ybTb) {
    int idx = blockIdx.x * 256 + threadIdx.x;   // p*128 + c
    int c = idx & 127, p = idx >> 7;
    int xx = p & 127, yy = p >> 7;
    float sum = 0.f;
    int tby = (yy & 1) ? 0 : 1;
    int tbx = (xx & 1) ? 0 : 1;
#pragma unroll
    for (int dt = 0; dt < 2; ++dt) {
        int t = tby + 2 * dt;
        int u2 = yy + 1 - t;
        if (u2 < 0 || u2 >= 128) continue;
        int u = u2 >> 1;
#pragma unroll
        for (int ds = 0; ds < 2; ++ds) {
            int s = tbx + 2 * ds;
            int v2 = xx + 1 - s;
            if (v2 < 0 || v2 >= 128) continue;
            int v = v2 >> 1;
            sum += (float)V[(size_t)(u * 64 + v) * RPAT + (t * 4 + s) * 128 + c];
        }
    }
    ybTb[idx] = (f16)(0.25f * sum);
}

// ---------------------------------------------------------------------------
// Wt[g][tap][oc][c] fp16 from conv_w (4,16,128,3,3) fp32
__global__ __launch_bounds__(256) void prep_w(const float* __restrict__ cw,
                                              f16* __restrict__ Wt) {
    int idx = blockIdx.x * 256 + threadIdx.x;
    if (idx >= 4 * 9 * 16 * 128) return;
    int g = idx / 18432, rem = idx % 18432;
    int tap = rem >> 11, oc = (rem >> 7) & 15, c = rem & 127;
    Wt[idx] = (f16)cw[(((g * 16 + oc) * 128 + c) * 9) + tap];
}

// ---------------------------------------------------------------------------
// Tap-decomposed implicit-GEMM grouped dilated conv via MFMA (fp16).
// 1D grid of 1024 blocks, XCD-swizzled: blockIdx%8 -> XCD (round-robin
// heuristic), batch b = (blockIdx>>1)&3 so each batch's 4.2 MB ybT slice
// stays resident in a dedicated XCD pair's L2 across all groups/taps.
__global__ __launch_bounds__(256) void final_conv_mfma(const f16* __restrict__ ybT,
                                                       const f16* __restrict__ Wt,
                                                       const float* __restrict__ cb,
                                                       float* __restrict__ out) {
    int id = blockIdx.x;
    int b = (id >> 1) & 3;                      // XCD pair <-> batch
    int unit = ((id >> 3) << 1) | (id & 1);     // 0..255
    int g = unit >> 6, rp = unit & 63;
    int tid = threadIdx.x, w = tid >> 6, lane = tid & 63;
    int y = rp * 2 + (w >> 1);
    int xbase = (w & 1) * 64;
    int r = 1 << g;                 // RATES = 1,2,4,8
    int m = lane & 15, q = lane >> 4;
    const f16* yB = ybT + (size_t)b * 16384 * 128;
    const f16* Wg = Wt + (size_t)g * 9 * 16 * 128;
    f32x4 acc[4];
#pragma unroll
    for (int mt = 0; mt < 4; ++mt) acc[mt] = (f32x4){0.f, 0.f, 0.f, 0.f};
#pragma unroll
    for (int tap = 0; tap < 9; ++tap) {
        int dy = (tap / 3 - 1) * r, dx = (tap % 3 - 1) * r;
        int yy = y + dy;
        bool rowok = (yy >= 0 && yy < 128);
        const f16* wrow = Wg + (tap * 16 + m) * 128 + q * 8;
        const f16* arow = yB + ((size_t)yy * 128) * 128 + q * 8;
#pragma unroll
        for (int ks = 0; ks < 4; ++ks) {
            f16x8 bfrag = *(const f16x8*)(wrow + ks * 32);
#pragma unroll
            for (int mt = 0; mt < 4; ++mt) {
                int xx = xbase + mt * 16 + m + dx;
                f16x8 afrag = {};
                if (rowok && xx >= 0 && xx < 128)
                    afrag = *(const f16x8*)(arow + (size_t)xx * 128 + ks * 32);
                acc[mt] = __builtin_amdgcn_mfma_f32_16x16x32_f16(afrag, bfrag, acc[mt], 0, 0, 0);
            }
        }
    }
    float bias = cb[g * 16 + m];
    float* orow = out + ((size_t)(b * 64 + g * 16 + m)) * 16384 + (size_t)y * 128;
#pragma unroll
    for (int mt = 0; mt < 4; ++mt)
#pragma unroll
        for (int ri = 0; ri < 4; ++ri) {
            int x = xbase + mt * 16 + q * 4 + ri;
            orow[x] = fmaxf(acc[mt][ri] + bias, 0.f);
        }
}

// ---------------------------------------------------------------------------
extern "C" void kernel_launch(void* const* d_in, const int* in_sizes, int n_in,
                              void* d_out, int out_size, void* d_ws, size_t ws_size,
                              hipStream_t stream) {
    const float* x1 = (const float*)d_in[0];        // (4,128,128,128)
    const float* x2 = (const float*)d_in[1];        // (4,64,64,64)
    const float* mask = (const float*)d_in[2];      // (4,1,128,128)
    const float* mask_all = (const float*)d_in[3];  // (4,1,64,64)
    const float* conv_w = (const float*)d_in[4];    // (4,16,128,3,3)
    const float* conv_b = (const float*)d_in[5];    // (4,16)
    float* out = (float*)d_out;                     // (4,64,128,128)

    char* ws = (char*)d_ws;
    f16*   Ph    = (f16*)  (ws + 0);            //  4,718,592 B
    float* rnorm = (float*)(ws + 4718592);      //     16,384 B
    int*   cidx  = (int*)  (ws + 4734976);      //     69,632 B (4 batches)
    int*   nk    = (int*)  (ws + 4804608);      //         32 B
    float* S     = (float*)(ws + 9469952);      // 67,108,864 B (reused as V f16)
    f16*   Ah    = (f16*)  (ws + 76578816);     // 33,554,432 B
    f16*   Rt    = (f16*)  (ws + 110133248);    // 16,777,216 B
    f16*   ybT   = (f16*)  (ws + 126910464);    // 16,777,216 B (all 4 batches)
    f16*   Wt    = (f16*)  (ws + 143687680);    //     73,728 B (end 143,761,408)
    f16*   V     = (f16*)S;                     // S dead after softmax

    prep_w<<<288, 256, 0, stream>>>(conv_w, Wt);
    compact_mask_all<<<4, 256, 0, stream>>>(mask, cidx, nk);
    for (int b = 0; b < 4; ++b) {
        const float* x2b = x2 + (size_t)b * 64 * 4096;
        const float* x1b = x1 + (size_t)b * 128 * 16384;
        const int* cb_idx = cidx + b * 4352;
        const int* nkb = nk + b * 2;
        build_P_norm<<<4096, 64, 0, stream>>>(x2b, Ph, rnorm);
        gemm_score_mfma<<<dim3(32, 32), 256, 0, stream>>>(Ph, cb_idx, rnorm, nkb, S);
        softmax_mask<<<4096, 256, 0, stream>>>(S, nkb, mask_all + (size_t)b * 4096, Ah);
        build_Rt<<<32768, 256, 0, stream>>>(x1b, cb_idx, nkb, Rt);
        gemm_deconv_mfma<<<dim3(16, 32), 256, 0, stream>>>(Ah, Rt, nkb, V);
        reconstruct<<<8192, 256, 0, stream>>>(V, ybT + (size_t)b * 16384 * 128);
    }
    final_conv_mfma<<<1024, 256, 0, stream>>>(ybT, Wt, conv_b, out);
}

// Round 6
// 796.568 us; speedup vs baseline: 6.8902x; 1.0167x over previous
//
#include <hip/hip_runtime.h>
#include <math.h>

typedef _Float16 f16;
typedef __attribute__((ext_vector_type(8))) _Float16 f16x8;
typedef __attribute__((ext_vector_type(4))) _Float16 f16x4;
typedef __attribute__((ext_vector_type(4))) float f32x4;

#define LPOS 4096      // 64*64 positions / patches
#define KPAT 576       // 64ch * 3*3 patch
#define RPAT 2048      // 128ch * 4*4 raw patch
#define PPAD 20736     // 144*144 padded positions for ybT

#define GLDS(g, l) __builtin_amdgcn_global_load_lds( \
    (const __attribute__((address_space(1))) void*)(g), \
    (__attribute__((address_space(3))) void*)(l), 16, 0, 0)

// ---------------------------------------------------------------------------
// Ph[pos][576] = fp16 3x3x64 patches of x2[b] (zero pad 1); rnorm[pos]
__global__ __launch_bounds__(64) void build_P_norm(const float* __restrict__ x2b,
                                                   f16* __restrict__ Ph,
                                                   float* __restrict__ rnorm) {
    int pos = blockIdx.x;
    int u = pos >> 6, v = pos & 63;
    int tid = threadIdx.x;
    float ss = 0.f;
    for (int k = tid; k < KPAT; k += 64) {
        int c = k / 9, r9 = k % 9;
        int di = r9 / 3, dj = r9 % 3;
        int yy = u + di - 1, xx = v + dj - 1;
        float val = 0.f;
        if (yy >= 0 && yy < 64 && xx >= 0 && xx < 64)
            val = x2b[c * 4096 + yy * 64 + xx];
        Ph[pos * KPAT + k] = (f16)val;
        ss += val * val;
    }
#pragma unroll
    for (int off = 32; off; off >>= 1) ss += __shfl_xor(ss, off, 64);
    if (tid == 0) rnorm[pos] = 1.f / fmaxf(sqrtf(ss), 1e-4f);
}

// ---------------------------------------------------------------------------
// All 4 batches in one launch: block b compacts mask[b] -> cidx[b], nk[b]
__global__ __launch_bounds__(256) void compact_mask_all(const float* __restrict__ mask,
                                                        int* __restrict__ cidx_all,
                                                        int* __restrict__ nk_all) {
    int b = blockIdx.x;
    const float* maskb = mask + (size_t)b * 16384;
    int* cidx = cidx_all + b * 4352;
    int* nk = nk_all + b * 2;
    int tid = threadIdx.x;
    int keep[16];
    int cnt = 0;
#pragma unroll
    for (int e = 0; e < 16; ++e) {
        int pos = tid * 16 + e;
        int pu = pos >> 6, pv = pos & 63;
        float s = 0.f;
        for (int t = 0; t < 4; ++t)
            for (int w = 0; w < 4; ++w) {
                int yy = 2 * pu - 1 + t, xx = 2 * pv - 1 + w;
                if (yy >= 0 && yy < 128 && xx >= 0 && xx < 128)
                    s += maskb[yy * 128 + xx];
            }
        keep[e] = (s == 0.f) ? 1 : 0;
        cnt += keep[e];
    }
    __shared__ int ps[256];
    ps[tid] = cnt;
    __syncthreads();
    for (int off = 1; off < 256; off <<= 1) {
        int v = (tid >= off) ? ps[tid - off] : 0;
        __syncthreads();
        ps[tid] += v;
        __syncthreads();
    }
    int total = ps[255];
    int base = ps[tid] - cnt;   // exclusive prefix
#pragma unroll
    for (int e = 0; e < 16; ++e)
        if (keep[e]) cidx[base++] = tid * 16 + e;
    for (int i = total + tid; i < 4352; i += 256) cidx[i] = 0;
    if (tid == 0) { nk[0] = total; nk[1] = (total + 31) & ~31; }
}

// ---------------------------------------------------------------------------
// Zero the 8-wide halo of the padded ybT buffer (all 4 batches)
__global__ __launch_bounds__(256) void zero_halo(f16* __restrict__ ybTp) {
    int idx = blockIdx.x * 256 + threadIdx.x;   // pos*16 + chunk
    int chunk = idx & 15;
    int pos = idx >> 4;                         // 0 .. 4*20736
    int pp = pos % PPAD;
    int yy = pp / 144, xx = pp % 144;
    if (yy >= 8 && yy < 136 && xx >= 8 && xx < 136) return;
    *(f16x8*)(ybTp + (size_t)pos * 128 + chunk * 8) = (f16x8){};
}

// ---------------------------------------------------------------------------
// S[m][j] = Ph[m] . Ph[cidx[j]] * rnorm[cidx[j]]   (fp16 MFMA, gathered B)
__global__ __launch_bounds__(256) void gemm_score_mfma(const f16* __restrict__ Ph,
                                                       const int* __restrict__ cidx,
                                                       const float* __restrict__ rnorm,
                                                       const int* __restrict__ nk,
                                                       float* __restrict__ S) {
    int n0 = blockIdx.x * 128;
    if (n0 >= nk[0]) return;    // fully-masked column tile
    __shared__ f16 Ash[128 * 32], Bsh[128 * 32];
    int tid = threadIdx.x;
    int w = tid >> 6, lane = tid & 63;
    int wy = w >> 1, wx = w & 1;
    int m0 = blockIdx.y * 128;
    f32x4 acc[4][4];
#pragma unroll
    for (int mt = 0; mt < 4; ++mt)
#pragma unroll
        for (int nt = 0; nt < 4; ++nt) acc[mt][nt] = (f32x4){0.f, 0.f, 0.f, 0.f};
    int srow = lane >> 2;
    int scol = (lane & 3) * 8;
    int q = (lane >> 4) * 8, r = lane & 15;
    const f16* Asrc[2]; const f16* Bsrc[2]; int ldso[2];
#pragma unroll
    for (int i = 0; i < 2; ++i) {
        int row = w * 32 + i * 16 + srow;
        ldso[i] = row * 32 + scol;
        Asrc[i] = Ph + (size_t)(m0 + row) * KPAT + scol;
        Bsrc[i] = Ph + (size_t)cidx[n0 + row] * KPAT + scol;
    }
    for (int k0 = 0; k0 < KPAT; k0 += 32) {
#pragma unroll
        for (int i = 0; i < 2; ++i) {
            GLDS(Asrc[i] + k0, Ash + ldso[i]);
            GLDS(Bsrc[i] + k0, Bsh + ldso[i]);
        }
        __syncthreads();
        f16x8 vb[4];
#pragma unroll
        for (int nt = 0; nt < 4; ++nt)
            vb[nt] = *(const f16x8*)&Bsh[(wx * 64 + nt * 16 + r) * 32 + q];
#pragma unroll
        for (int mt = 0; mt < 4; ++mt) {
            f16x8 va = *(const f16x8*)&Ash[(wy * 64 + mt * 16 + r) * 32 + q];
#pragma unroll
            for (int nt = 0; nt < 4; ++nt)
                acc[mt][nt] = __builtin_amdgcn_mfma_f32_16x16x32_f16(va, vb[nt], acc[mt][nt], 0, 0, 0);
        }
        __syncthreads();
    }
    int qq = lane >> 4;
#pragma unroll
    for (int nt = 0; nt < 4; ++nt) {
        int col = n0 + wx * 64 + nt * 16 + r;
        float rn = rnorm[cidx[col]];
#pragma unroll
        for (int mt = 0; mt < 4; ++mt)
#pragma unroll
            for (int ri = 0; ri < 4; ++ri) {
                int row = m0 + wy * 64 + mt * 16 + qq * 4 + ri;
                S[(size_t)row * LPOS + col] = acc[mt][nt][ri] * rn;
            }
    }
}

// ---------------------------------------------------------------------------
// Masked softmax over compacted columns (float4 reads, f16x4 writes)
__global__ __launch_bounds__(256) void softmax_mask(const float* __restrict__ S,
                                                    const int* __restrict__ nk,
                                                    const float* __restrict__ mab,
                                                    f16* __restrict__ Ah) {
    int pos = blockIdx.x;
    int tid = threadIdx.x;
    int nkeep = nk[0], kpad = nk[1];
    float ma = mab[pos];
    float sc = 10.0f * ma;
    const float4* S4 = (const float4*)(S + (size_t)pos * LPOS);
    float v[16];
    float vmax = (nkeep < LPOS) ? 0.f : -3.0e38f;
#pragma unroll
    for (int i = 0; i < 4; ++i) {
        int jb = (tid + i * 256) * 4;
        float4 x4 = S4[tid + i * 256];
#pragma unroll
        for (int e = 0; e < 4; ++e) {
            float xv = (&x4.x)[e];
            float x = (jb + e < nkeep) ? xv * sc : -3.0e38f;
            v[i * 4 + e] = x;
            vmax = fmaxf(vmax, x);
        }
    }
#pragma unroll
    for (int off = 32; off; off >>= 1) vmax = fmaxf(vmax, __shfl_xor(vmax, off, 64));
    __shared__ float sred[4];
    int wid = tid >> 6;
    if ((tid & 63) == 0) sred[wid] = vmax;
    __syncthreads();
    vmax = fmaxf(fmaxf(sred[0], sred[1]), fmaxf(sred[2], sred[3]));
    __syncthreads();
    float ssum = 0.f;
#pragma unroll
    for (int i = 0; i < 16; ++i) {
        float e = (v[i] > -1.0e37f) ? __expf(v[i] - vmax) : 0.f;
        v[i] = e;
        ssum += e;
    }
#pragma unroll
    for (int off = 32; off; off >>= 1) ssum += __shfl_xor(ssum, off, 64);
    if ((tid & 63) == 0) sred[wid] = ssum;
    __syncthreads();
    float total = sred[0] + sred[1] + sred[2] + sred[3]
                + (float)(LPOS - nkeep) * __expf(-vmax);
    float inv = 1.f / total;
#pragma unroll
    for (int i = 0; i < 4; ++i) {
        int jb = (tid + i * 256) * 4;
        if (jb >= kpad) continue;
        f16x4 h;
#pragma unroll
        for (int e = 0; e < 4; ++e)
            h[e] = (jb + e < nkeep) ? (f16)(v[i * 4 + e] * inv * ma) : (f16)0.f;
        *(f16x4*)(Ah + (size_t)pos * LPOS + jb) = h;
    }
}

// ---------------------------------------------------------------------------
// Rt[n][j] fp16, n = (t*4+s)*128 + c, patch p = cidx[j] (compacted gather)
__global__ __launch_bounds__(256) void build_Rt(const float* __restrict__ x1b,
                                                const int* __restrict__ cidx,
                                                const int* __restrict__ nk,
                                                f16* __restrict__ Rt) {
    int idx = blockIdx.x * 256 + threadIdx.x;   // n*4096 + j
    int j = idx & 4095, n = idx >> 12;
    if (j >= nk[1]) return;
    int p = cidx[j];
    int pu = p >> 6, pv = p & 63;
    int t = (n >> 9) & 3, s = (n >> 7) & 3, c = n & 127;
    int yy = 2 * pu - 1 + t, xx = 2 * pv - 1 + s;
    float val = 0.f;
    if (yy >= 0 && yy < 128 && xx >= 0 && xx < 128)
        val = x1b[c * 16384 + yy * 128 + xx];
    Rt[idx] = (f16)val;
}

// ---------------------------------------------------------------------------
// V[m][n] = sum_{k<kpad} A[m][k] * Bt[n][k]   (fp16 MFMA, dynamic K, fp16 out)
// 1D grid 512: XCD (id&7) owns 4 m-tiles -> A slice (3 MB) L2-resident.
__global__ __launch_bounds__(256) void gemm_deconv_mfma(const f16* __restrict__ A,
                                                        const f16* __restrict__ Bt,
                                                        const int* __restrict__ nk,
                                                        f16* __restrict__ V) {
    __shared__ f16 Ash[128 * 32], Bsh[128 * 32];
    int kpad = nk[1];
    int id = blockIdx.x;
    int m0 = ((id & 7) * 4 + ((id >> 3) & 3)) * 128;
    int n0 = (id >> 5) * 128;
    int tid = threadIdx.x;
    int w = tid >> 6, lane = tid & 63;
    int wy = w >> 1, wx = w & 1;
    f32x4 acc[4][4];
#pragma unroll
    for (int mt = 0; mt < 4; ++mt)
#pragma unroll
        for (int nt = 0; nt < 4; ++nt) acc[mt][nt] = (f32x4){0.f, 0.f, 0.f, 0.f};
    int srow = lane >> 2;
    int scol = (lane & 3) * 8;
    int q = (lane >> 4) * 8, r = lane & 15;
    for (int k0 = 0; k0 < kpad; k0 += 32) {
#pragma unroll
        for (int i = 0; i < 2; ++i) {
            int row = w * 32 + i * 16 + srow;
            int ldso = row * 32 + scol;
            GLDS(A + (size_t)(m0 + row) * LPOS + k0 + scol, Ash + ldso);
            GLDS(Bt + (size_t)(n0 + row) * LPOS + k0 + scol, Bsh + ldso);
        }
        __syncthreads();
        f16x8 vb[4];
#pragma unroll
        for (int nt = 0; nt < 4; ++nt)
            vb[nt] = *(const f16x8*)&Bsh[(wx * 64 + nt * 16 + r) * 32 + q];
#pragma unroll
        for (int mt = 0; mt < 4; ++mt) {
            f16x8 va = *(const f16x8*)&Ash[(wy * 64 + mt * 16 + r) * 32 + q];
#pragma unroll
            for (int nt = 0; nt < 4; ++nt)
                acc[mt][nt] = __builtin_amdgcn_mfma_f32_16x16x32_f16(va, vb[nt], acc[mt][nt], 0, 0, 0);
        }
        __syncthreads();
    }
    int qq = lane >> 4;
#pragma unroll
    for (int mt = 0; mt < 4; ++mt)
#pragma unroll
        for (int nt = 0; nt < 4; ++nt) {
            int col = n0 + wx * 64 + nt * 16 + r;
#pragma unroll
            for (int ri = 0; ri < 4; ++ri) {
                int row = m0 + wy * 64 + mt * 16 + qq * 4 + ri;
                V[(size_t)row * RPAT + col] = (f16)acc[mt][nt][ri];
            }
        }
}

// ---------------------------------------------------------------------------
// ybTp[b][(yy+8)*144+(xx+8)][c] = 0.25 * sum over valid taps of V  (padded)
__global__ __launch_bounds__(256) void reconstruct(const f16* __restrict__ V,
                                                   f16* __restrict__ ybTpb) {
    int idx = blockIdx.x * 256 + threadIdx.x;   // p*128 + c
    int c = idx & 127, p = idx >> 7;
    int xx = p & 127, yy = p >> 7;
    float sum = 0.f;
    int tby = (yy & 1) ? 0 : 1;
    int tbx = (xx & 1) ? 0 : 1;
#pragma unroll
    for (int dt = 0; dt < 2; ++dt) {
        int t = tby + 2 * dt;
        int u2 = yy + 1 - t;
        if (u2 < 0 || u2 >= 128) continue;
        int u = u2 >> 1;
#pragma unroll
        for (int ds = 0; ds < 2; ++ds) {
            int s = tbx + 2 * ds;
            int v2 = xx + 1 - s;
            if (v2 < 0 || v2 >= 128) continue;
            int v = v2 >> 1;
            sum += (float)V[(size_t)(u * 64 + v) * RPAT + (t * 4 + s) * 128 + c];
        }
    }
    ybTpb[((size_t)(yy + 8) * 144 + (xx + 8)) * 128 + c] = (f16)(0.25f * sum);
}

// ---------------------------------------------------------------------------
// Wt[g][tap][oc][c] fp16 from conv_w (4,16,128,3,3) fp32
__global__ __launch_bounds__(256) void prep_w(const float* __restrict__ cw,
                                              f16* __restrict__ Wt) {
    int idx = blockIdx.x * 256 + threadIdx.x;
    if (idx >= 4 * 9 * 16 * 128) return;
    int g = idx / 18432, rem = idx % 18432;
    int tap = rem >> 11, oc = (rem >> 7) & 15, c = rem & 127;
    Wt[idx] = (f16)cw[(((g * 16 + oc) * 128 + c) * 9) + tap];
}

// ---------------------------------------------------------------------------
// Tap-decomposed implicit-GEMM grouped dilated conv via MFMA (fp16).
// Padded input (zero halo) -> unconditional A-loads, deep pipelining.
// XCD partition p = id&7 = b*2 + yhalf: per-XCD working set ~3 MB < 4 MB L2.
__global__ __launch_bounds__(256, 4) void final_conv_mfma(const f16* __restrict__ ybTp,
                                                          const f16* __restrict__ Wt,
                                                          const float* __restrict__ cb,
                                                          float* __restrict__ out) {
    int id = blockIdx.x;
    int p = id & 7;
    int b = p >> 1, yhalf = p & 1;
    int unit = id >> 3;             // 0..127
    int g = unit >> 5;              // 0..3
    int rl = unit & 31;             // 0..31
    int tid = threadIdx.x, w = tid >> 6, lane = tid & 63;
    int y = yhalf * 64 + rl * 2 + (w >> 1);
    int xbase = (w & 1) * 64;
    int r = 1 << g;                 // RATES = 1,2,4,8
    int m = lane & 15, q = lane >> 4;
    const f16* yB = ybTp + (size_t)b * PPAD * 128;
    const f16* Wg = Wt + (size_t)g * 9 * 16 * 128;
    f32x4 acc[4];
#pragma unroll
    for (int mt = 0; mt < 4; ++mt) acc[mt] = (f32x4){0.f, 0.f, 0.f, 0.f};
#pragma unroll
    for (int tap = 0; tap < 9; ++tap) {
        int dy = (tap / 3 - 1) * r, dx = (tap % 3 - 1) * r;
        const f16* wrow = Wg + (tap * 16 + m) * 128 + q * 8;
        const f16* arow = yB + ((size_t)(y + dy + 8) * 144 + 8 + dx) * 128 + q * 8;
#pragma unroll
        for (int ks = 0; ks < 4; ++ks) {
            f16x8 bfrag = *(const f16x8*)(wrow + ks * 32);
#pragma unroll
            for (int mt = 0; mt < 4; ++mt) {
                int xx = xbase + mt * 16 + m;
                f16x8 afrag = *(const f16x8*)(arow + (size_t)xx * 128 + ks * 32);
                acc[mt] = __builtin_amdgcn_mfma_f32_16x16x32_f16(afrag, bfrag, acc[mt], 0, 0, 0);
            }
        }
    }
    float bias = cb[g * 16 + m];
    float* orow = out + ((size_t)(b * 64 + g * 16 + m)) * 16384 + (size_t)y * 128;
#pragma unroll
    for (int mt = 0; mt < 4; ++mt)
#pragma unroll
        for (int ri = 0; ri < 4; ++ri) {
            int x = xbase + mt * 16 + q * 4 + ri;
            orow[x] = fmaxf(acc[mt][ri] + bias, 0.f);
        }
}

// ---------------------------------------------------------------------------
extern "C" void kernel_launch(void* const* d_in, const int* in_sizes, int n_in,
                              void* d_out, int out_size, void* d_ws, size_t ws_size,
                              hipStream_t stream) {
    const float* x1 = (const float*)d_in[0];        // (4,128,128,128)
    const float* x2 = (const float*)d_in[1];        // (4,64,64,64)
    const float* mask = (const float*)d_in[2];      // (4,1,128,128)
    const float* mask_all = (const float*)d_in[3];  // (4,1,64,64)
    const float* conv_w = (const float*)d_in[4];    // (4,16,128,3,3)
    const float* conv_b = (const float*)d_in[5];    // (4,16)
    float* out = (float*)d_out;                     // (4,64,128,128)

    char* ws = (char*)d_ws;
    f16*   Ph    = (f16*)  (ws + 0);            //  4,718,592 B
    float* rnorm = (float*)(ws + 4718592);      //     16,384 B
    int*   cidx  = (int*)  (ws + 4734976);      //     69,632 B (4 batches)
    int*   nk    = (int*)  (ws + 4804608);      //         32 B
    float* S     = (float*)(ws + 9469952);      // 67,108,864 B (reused as V f16)
    f16*   Ah    = (f16*)  (ws + 76578816);     // 33,554,432 B
    f16*   Rt    = (f16*)  (ws + 110133248);    // 16,777,216 B
    f16*   ybTp  = (f16*)  (ws + 126910464);    // 21,233,664 B (padded, 4 batches)
    f16*   Wt    = (f16*)  (ws + 148144128);    //     73,728 B (end 148,217,856)
    f16*   V     = (f16*)S;                     // S dead after softmax

    prep_w<<<288, 256, 0, stream>>>(conv_w, Wt);
    compact_mask_all<<<4, 256, 0, stream>>>(mask, cidx, nk);
    zero_halo<<<5184, 256, 0, stream>>>(ybTp);
    for (int b = 0; b < 4; ++b) {
        const float* x2b = x2 + (size_t)b * 64 * 4096;
        const float* x1b = x1 + (size_t)b * 128 * 16384;
        const int* cb_idx = cidx + b * 4352;
        const int* nkb = nk + b * 2;
        build_P_norm<<<4096, 64, 0, stream>>>(x2b, Ph, rnorm);
        gemm_score_mfma<<<dim3(32, 32), 256, 0, stream>>>(Ph, cb_idx, rnorm, nkb, S);
        softmax_mask<<<4096, 256, 0, stream>>>(S, nkb, mask_all + (size_t)b * 4096, Ah);
        build_Rt<<<32768, 256, 0, stream>>>(x1b, cb_idx, nkb, Rt);
        gemm_deconv_mfma<<<512, 256, 0, stream>>>(Ah, Rt, nkb, V);
        reconstruct<<<8192, 256, 0, stream>>>(V, ybTp + (size_t)b * PPAD * 128);
    }
    final_conv_mfma<<<1024, 256, 0, stream>>>(ybTp, Wt, conv_b, out);
}

// Round 7
// 785.178 us; speedup vs baseline: 6.9901x; 1.0145x over previous
//
#include <hip/hip_runtime.h>
#include <math.h>

typedef _Float16 f16;
typedef __attribute__((ext_vector_type(8))) _Float16 f16x8;
typedef __attribute__((ext_vector_type(4))) _Float16 f16x4;
typedef __attribute__((ext_vector_type(4))) float f32x4;

#define LPOS 4096      // 64*64 positions / patches
#define KPAT 576       // 64ch * 3*3 patch
#define RPAT 2048      // 128ch * 4*4 raw patch
#define PPAD 20736     // 144*144 padded positions for ybT

#define GLDS(g, l) __builtin_amdgcn_global_load_lds( \
    (const __attribute__((address_space(1))) void*)(g), \
    (__attribute__((address_space(3))) void*)(l), 16, 0, 0)

// ---------------------------------------------------------------------------
// Ph[pos][576] = fp16 3x3x64 patches of x2[b] (zero pad 1); rnorm[pos]
__global__ __launch_bounds__(64) void build_P_norm(const float* __restrict__ x2b,
                                                   f16* __restrict__ Ph,
                                                   float* __restrict__ rnorm) {
    int pos = blockIdx.x;
    int u = pos >> 6, v = pos & 63;
    int tid = threadIdx.x;
    float ss = 0.f;
    for (int k = tid; k < KPAT; k += 64) {
        int c = k / 9, r9 = k % 9;
        int di = r9 / 3, dj = r9 % 3;
        int yy = u + di - 1, xx = v + dj - 1;
        float val = 0.f;
        if (yy >= 0 && yy < 64 && xx >= 0 && xx < 64)
            val = x2b[c * 4096 + yy * 64 + xx];
        Ph[pos * KPAT + k] = (f16)val;
        ss += val * val;
    }
#pragma unroll
    for (int off = 32; off; off >>= 1) ss += __shfl_xor(ss, off, 64);
    if (tid == 0) rnorm[pos] = 1.f / fmaxf(sqrtf(ss), 1e-4f);
}

// ---------------------------------------------------------------------------
// All 4 batches in one launch: block b compacts mask[b] -> cidx[b], nk[b]
__global__ __launch_bounds__(256) void compact_mask_all(const float* __restrict__ mask,
                                                        int* __restrict__ cidx_all,
                                                        int* __restrict__ nk_all) {
    int b = blockIdx.x;
    const float* maskb = mask + (size_t)b * 16384;
    int* cidx = cidx_all + b * 4352;
    int* nk = nk_all + b * 2;
    int tid = threadIdx.x;
    int keep[16];
    int cnt = 0;
#pragma unroll
    for (int e = 0; e < 16; ++e) {
        int pos = tid * 16 + e;
        int pu = pos >> 6, pv = pos & 63;
        float s = 0.f;
        for (int t = 0; t < 4; ++t)
            for (int w = 0; w < 4; ++w) {
                int yy = 2 * pu - 1 + t, xx = 2 * pv - 1 + w;
                if (yy >= 0 && yy < 128 && xx >= 0 && xx < 128)
                    s += maskb[yy * 128 + xx];
            }
        keep[e] = (s == 0.f) ? 1 : 0;
        cnt += keep[e];
    }
    __shared__ int ps[256];
    ps[tid] = cnt;
    __syncthreads();
    for (int off = 1; off < 256; off <<= 1) {
        int v = (tid >= off) ? ps[tid - off] : 0;
        __syncthreads();
        ps[tid] += v;
        __syncthreads();
    }
    int total = ps[255];
    int base = ps[tid] - cnt;   // exclusive prefix
#pragma unroll
    for (int e = 0; e < 16; ++e)
        if (keep[e]) cidx[base++] = tid * 16 + e;
    for (int i = total + tid; i < 4352; i += 256) cidx[i] = 0;
    if (tid == 0) { nk[0] = total; nk[1] = (total + 31) & ~31; }
}

// ---------------------------------------------------------------------------
// Zero the 8-wide halo of the padded ybT buffer (all 4 batches)
__global__ __launch_bounds__(256) void zero_halo(f16* __restrict__ ybTp) {
    int idx = blockIdx.x * 256 + threadIdx.x;   // pos*16 + chunk
    int chunk = idx & 15;
    int pos = idx >> 4;                         // 0 .. 4*20736
    int pp = pos % PPAD;
    int yy = pp / 144, xx = pp % 144;
    if (yy >= 8 && yy < 136 && xx >= 8 && xx < 136) return;
    *(f16x8*)(ybTp + (size_t)pos * 128 + chunk * 8) = (f16x8){};
}

// ---------------------------------------------------------------------------
// S[m][j] = Ph[m] . Ph[cidx[j]] * rnorm[cidx[j]]   (fp16 MFMA, gathered B)
// LDS XOR-swizzle: 16B block cblk of row stored at slot cblk^((row>>1)&3).
__global__ __launch_bounds__(256) void gemm_score_mfma(const f16* __restrict__ Ph,
                                                       const int* __restrict__ cidx,
                                                       const float* __restrict__ rnorm,
                                                       const int* __restrict__ nk,
                                                       float* __restrict__ S) {
    int n0 = blockIdx.x * 128;
    if (n0 >= nk[0]) return;    // fully-masked column tile
    __shared__ f16 Ash[128 * 32], Bsh[128 * 32];
    int tid = threadIdx.x;
    int w = tid >> 6, lane = tid & 63;
    int wy = w >> 1, wx = w & 1;
    int m0 = blockIdx.y * 128;
    f32x4 acc[4][4];
#pragma unroll
    for (int mt = 0; mt < 4; ++mt)
#pragma unroll
        for (int nt = 0; nt < 4; ++nt) acc[mt][nt] = (f32x4){0.f, 0.f, 0.f, 0.f};
    int srow = lane >> 2;                          // 0..15
    int cblk = lane & 3;                           // LDS slot 16B block
    int scol = (cblk ^ ((srow >> 1) & 3)) * 8;     // swizzled global col (elems)
    int dcol = cblk * 8;
    int r = lane & 15, qb = lane >> 4;
    int sw = (r >> 1) & 3;
    int qcol = (qb ^ sw) * 8;                      // de-swizzled read col
    const f16* Asrc[2]; const f16* Bsrc[2]; int ldso[2];
#pragma unroll
    for (int i = 0; i < 2; ++i) {
        int row = w * 32 + i * 16 + srow;
        ldso[i] = row * 32 + dcol;
        Asrc[i] = Ph + (size_t)(m0 + row) * KPAT + scol;
        Bsrc[i] = Ph + (size_t)cidx[n0 + row] * KPAT + scol;
    }
    for (int k0 = 0; k0 < KPAT; k0 += 32) {
#pragma unroll
        for (int i = 0; i < 2; ++i) {
            GLDS(Asrc[i] + k0, Ash + ldso[i]);
            GLDS(Bsrc[i] + k0, Bsh + ldso[i]);
        }
        __syncthreads();
        f16x8 vb[4];
#pragma unroll
        for (int nt = 0; nt < 4; ++nt)
            vb[nt] = *(const f16x8*)&Bsh[(wx * 64 + nt * 16 + r) * 32 + qcol];
#pragma unroll
        for (int mt = 0; mt < 4; ++mt) {
            f16x8 va = *(const f16x8*)&Ash[(wy * 64 + mt * 16 + r) * 32 + qcol];
#pragma unroll
            for (int nt = 0; nt < 4; ++nt)
                acc[mt][nt] = __builtin_amdgcn_mfma_f32_16x16x32_f16(va, vb[nt], acc[mt][nt], 0, 0, 0);
        }
        __syncthreads();
    }
    int qq = lane >> 4;
#pragma unroll
    for (int nt = 0; nt < 4; ++nt) {
        int col = n0 + wx * 64 + nt * 16 + r;
        float rn = rnorm[cidx[col]];
#pragma unroll
        for (int mt = 0; mt < 4; ++mt)
#pragma unroll
            for (int ri = 0; ri < 4; ++ri) {
                int row = m0 + wy * 64 + mt * 16 + qq * 4 + ri;
                S[(size_t)row * LPOS + col] = acc[mt][nt][ri] * rn;
            }
    }
}

// ---------------------------------------------------------------------------
// Masked softmax over compacted columns (float4 reads, f16x4 writes)
__global__ __launch_bounds__(256) void softmax_mask(const float* __restrict__ S,
                                                    const int* __restrict__ nk,
                                                    const float* __restrict__ mab,
                                                    f16* __restrict__ Ah) {
    int pos = blockIdx.x;
    int tid = threadIdx.x;
    int nkeep = nk[0], kpad = nk[1];
    float ma = mab[pos];
    float sc = 10.0f * ma;
    const float4* S4 = (const float4*)(S + (size_t)pos * LPOS);
    float v[16];
    float vmax = (nkeep < LPOS) ? 0.f : -3.0e38f;
#pragma unroll
    for (int i = 0; i < 4; ++i) {
        int jb = (tid + i * 256) * 4;
        float4 x4 = S4[tid + i * 256];
#pragma unroll
        for (int e = 0; e < 4; ++e) {
            float xv = (&x4.x)[e];
            float x = (jb + e < nkeep) ? xv * sc : -3.0e38f;
            v[i * 4 + e] = x;
            vmax = fmaxf(vmax, x);
        }
    }
#pragma unroll
    for (int off = 32; off; off >>= 1) vmax = fmaxf(vmax, __shfl_xor(vmax, off, 64));
    __shared__ float sred[4];
    int wid = tid >> 6;
    if ((tid & 63) == 0) sred[wid] = vmax;
    __syncthreads();
    vmax = fmaxf(fmaxf(sred[0], sred[1]), fmaxf(sred[2], sred[3]));
    __syncthreads();
    float ssum = 0.f;
#pragma unroll
    for (int i = 0; i < 16; ++i) {
        float e = (v[i] > -1.0e37f) ? __expf(v[i] - vmax) : 0.f;
        v[i] = e;
        ssum += e;
    }
#pragma unroll
    for (int off = 32; off; off >>= 1) ssum += __shfl_xor(ssum, off, 64);
    if ((tid & 63) == 0) sred[wid] = ssum;
    __syncthreads();
    float total = sred[0] + sred[1] + sred[2] + sred[3]
                + (float)(LPOS - nkeep) * __expf(-vmax);
    float inv = 1.f / total;
#pragma unroll
    for (int i = 0; i < 4; ++i) {
        int jb = (tid + i * 256) * 4;
        if (jb >= kpad) continue;
        f16x4 h;
#pragma unroll
        for (int e = 0; e < 4; ++e)
            h[e] = (jb + e < nkeep) ? (f16)(v[i * 4 + e] * inv * ma) : (f16)0.f;
        *(f16x4*)(Ah + (size_t)pos * LPOS + jb) = h;
    }
}

// ---------------------------------------------------------------------------
// Rt[n][j] fp16, n = (t*4+s)*128 + c, patch p = cidx[j] (compacted gather)
__global__ __launch_bounds__(256) void build_Rt(const float* __restrict__ x1b,
                                                const int* __restrict__ cidx,
                                                const int* __restrict__ nk,
                                                f16* __restrict__ Rt) {
    int idx = blockIdx.x * 256 + threadIdx.x;   // n*4096 + j
    int j = idx & 4095, n = idx >> 12;
    if (j >= nk[1]) return;
    int p = cidx[j];
    int pu = p >> 6, pv = p & 63;
    int t = (n >> 9) & 3, s = (n >> 7) & 3, c = n & 127;
    int yy = 2 * pu - 1 + t, xx = 2 * pv - 1 + s;
    float val = 0.f;
    if (yy >= 0 && yy < 128 && xx >= 0 && xx < 128)
        val = x1b[c * 16384 + yy * 128 + xx];
    Rt[idx] = (f16)val;
}

// ---------------------------------------------------------------------------
// V[m][n] = sum_{k<kpad} A[m][k] * Bt[n][k]   (fp16 MFMA, dynamic K, fp16 out)
// 1D grid 512: XCD (id&7) owns 4 m-tiles -> A slice (3 MB) L2-resident.
// LDS XOR-swizzled (same scheme as gemm_score_mfma).
__global__ __launch_bounds__(256) void gemm_deconv_mfma(const f16* __restrict__ A,
                                                        const f16* __restrict__ Bt,
                                                        const int* __restrict__ nk,
                                                        f16* __restrict__ V) {
    __shared__ f16 Ash[128 * 32], Bsh[128 * 32];
    int kpad = nk[1];
    int id = blockIdx.x;
    int m0 = ((id & 7) * 4 + ((id >> 3) & 3)) * 128;
    int n0 = (id >> 5) * 128;
    int tid = threadIdx.x;
    int w = tid >> 6, lane = tid & 63;
    int wy = w >> 1, wx = w & 1;
    f32x4 acc[4][4];
#pragma unroll
    for (int mt = 0; mt < 4; ++mt)
#pragma unroll
        for (int nt = 0; nt < 4; ++nt) acc[mt][nt] = (f32x4){0.f, 0.f, 0.f, 0.f};
    int srow = lane >> 2;
    int cblk = lane & 3;
    int scol = (cblk ^ ((srow >> 1) & 3)) * 8;
    int dcol = cblk * 8;
    int r = lane & 15, qb = lane >> 4;
    int sw = (r >> 1) & 3;
    int qcol = (qb ^ sw) * 8;
    for (int k0 = 0; k0 < kpad; k0 += 32) {
#pragma unroll
        for (int i = 0; i < 2; ++i) {
            int row = w * 32 + i * 16 + srow;
            int ldso = row * 32 + dcol;
            GLDS(A + (size_t)(m0 + row) * LPOS + k0 + scol, Ash + ldso);
            GLDS(Bt + (size_t)(n0 + row) * LPOS + k0 + scol, Bsh + ldso);
        }
        __syncthreads();
        f16x8 vb[4];
#pragma unroll
        for (int nt = 0; nt < 4; ++nt)
            vb[nt] = *(const f16x8*)&Bsh[(wx * 64 + nt * 16 + r) * 32 + qcol];
#pragma unroll
        for (int mt = 0; mt < 4; ++mt) {
            f16x8 va = *(const f16x8*)&Ash[(wy * 64 + mt * 16 + r) * 32 + qcol];
#pragma unroll
            for (int nt = 0; nt < 4; ++nt)
                acc[mt][nt] = __builtin_amdgcn_mfma_f32_16x16x32_f16(va, vb[nt], acc[mt][nt], 0, 0, 0);
        }
        __syncthreads();
    }
    int qq = lane >> 4;
#pragma unroll
    for (int mt = 0; mt < 4; ++mt)
#pragma unroll
        for (int nt = 0; nt < 4; ++nt) {
            int col = n0 + wx * 64 + nt * 16 + r;
#pragma unroll
            for (int ri = 0; ri < 4; ++ri) {
                int row = m0 + wy * 64 + mt * 16 + qq * 4 + ri;
                V[(size_t)row * RPAT + col] = (f16)acc[mt][nt][ri];
            }
        }
}

// ---------------------------------------------------------------------------
// ybTp[b][(yy+8)*144+(xx+8)][c] = 0.25 * sum over valid taps of V  (padded)
__global__ __launch_bounds__(256) void reconstruct(const f16* __restrict__ V,
                                                   f16* __restrict__ ybTpb) {
    int idx = blockIdx.x * 256 + threadIdx.x;   // p*128 + c
    int c = idx & 127, p = idx >> 7;
    int xx = p & 127, yy = p >> 7;
    float sum = 0.f;
    int tby = (yy & 1) ? 0 : 1;
    int tbx = (xx & 1) ? 0 : 1;
#pragma unroll
    for (int dt = 0; dt < 2; ++dt) {
        int t = tby + 2 * dt;
        int u2 = yy + 1 - t;
        if (u2 < 0 || u2 >= 128) continue;
        int u = u2 >> 1;
#pragma unroll
        for (int ds = 0; ds < 2; ++ds) {
            int s = tbx + 2 * ds;
            int v2 = xx + 1 - s;
            if (v2 < 0 || v2 >= 128) continue;
            int v = v2 >> 1;
            sum += (float)V[(size_t)(u * 64 + v) * RPAT + (t * 4 + s) * 128 + c];
        }
    }
    ybTpb[((size_t)(yy + 8) * 144 + (xx + 8)) * 128 + c] = (f16)(0.25f * sum);
}

// ---------------------------------------------------------------------------
// Wt[g][tap][oc][c] fp16 from conv_w (4,16,128,3,3) fp32
__global__ __launch_bounds__(256) void prep_w(const float* __restrict__ cw,
                                              f16* __restrict__ Wt) {
    int idx = blockIdx.x * 256 + threadIdx.x;
    if (idx >= 4 * 9 * 16 * 128) return;
    int g = idx / 18432, rem = idx % 18432;
    int tap = rem >> 11, oc = (rem >> 7) & 15, c = rem & 127;
    Wt[idx] = (f16)cw[(((g * 16 + oc) * 128 + c) * 9) + tap];
}

// ---------------------------------------------------------------------------
// Tap-decomposed implicit-GEMM grouped dilated conv via MFMA (fp16).
// Explicit 2-stage software pipeline over 36 flattened (tap,ks) stages:
// parity-double-buffered fragments force loads of stage t+1 to issue
// before stage t's MFMAs, so waits become vmcnt(5) not vmcnt(0).
__global__ __launch_bounds__(256, 4) void final_conv_mfma(const f16* __restrict__ ybTp,
                                                          const f16* __restrict__ Wt,
                                                          const float* __restrict__ cb,
                                                          float* __restrict__ out) {
    int id = blockIdx.x;
    int p = id & 7;
    int b = p >> 1, yhalf = p & 1;
    int unit = id >> 3;             // 0..127
    int g = unit >> 5;              // 0..3
    int rl = unit & 31;             // 0..31
    int tid = threadIdx.x, w = tid >> 6, lane = tid & 63;
    int y = yhalf * 64 + rl * 2 + (w >> 1);
    int xbase = (w & 1) * 64;
    int r = 1 << g;                 // RATES = 1,2,4,8
    int m = lane & 15, q = lane >> 4;
    const f16* yB = ybTp + (size_t)b * PPAD * 128;
    const f16* Wg = Wt + (size_t)g * 9 * 16 * 128 + m * 128 + q * 8;
    int aoff = (xbase + m) * 128 + q * 8;
    const f16* aptr[9];
#pragma unroll
    for (int tap = 0; tap < 9; ++tap) {
        int dy = (tap / 3 - 1) * r, dx = (tap % 3 - 1) * r;
        aptr[tap] = yB + ((size_t)(y + dy + 8) * 144 + 8 + dx) * 128 + aoff;
    }
    f32x4 acc[4];
#pragma unroll
    for (int mt = 0; mt < 4; ++mt) acc[mt] = (f32x4){0.f, 0.f, 0.f, 0.f};
    f16x8 af[2][4], bf[2];
#pragma unroll
    for (int mt = 0; mt < 4; ++mt) af[0][mt] = *(const f16x8*)(aptr[0] + mt * 2048);
    bf[0] = *(const f16x8*)(Wg);
#pragma unroll
    for (int t = 0; t < 36; ++t) {
        int pb = t & 1;
        if (t < 35) {
            int tn = t + 1, tap = tn >> 2, ks = tn & 3;
#pragma unroll
            for (int mt = 0; mt < 4; ++mt)
                af[pb ^ 1][mt] = *(const f16x8*)(aptr[tap] + ks * 32 + mt * 2048);
            bf[pb ^ 1] = *(const f16x8*)(Wg + tap * 2048 + ks * 32);
        }
#pragma unroll
        for (int mt = 0; mt < 4; ++mt)
            acc[mt] = __builtin_amdgcn_mfma_f32_16x16x32_f16(af[pb][mt], bf[pb], acc[mt], 0, 0, 0);
    }
    float bias = cb[g * 16 + m];
    float* orow = out + ((size_t)(b * 64 + g * 16 + m)) * 16384 + (size_t)y * 128;
#pragma unroll
    for (int mt = 0; mt < 4; ++mt)
#pragma unroll
        for (int ri = 0; ri < 4; ++ri) {
            int x = xbase + mt * 16 + q * 4 + ri;
            orow[x] = fmaxf(acc[mt][ri] + bias, 0.f);
        }
}

// ---------------------------------------------------------------------------
extern "C" void kernel_launch(void* const* d_in, const int* in_sizes, int n_in,
                              void* d_out, int out_size, void* d_ws, size_t ws_size,
                              hipStream_t stream) {
    const float* x1 = (const float*)d_in[0];        // (4,128,128,128)
    const float* x2 = (const float*)d_in[1];        // (4,64,64,64)
    const float* mask = (const float*)d_in[2];      // (4,1,128,128)
    const float* mask_all = (const float*)d_in[3];  // (4,1,64,64)
    const float* conv_w = (const float*)d_in[4];    // (4,16,128,3,3)
    const float* conv_b = (const float*)d_in[5];    // (4,16)
    float* out = (float*)d_out;                     // (4,64,128,128)

    char* ws = (char*)d_ws;
    f16*   Ph    = (f16*)  (ws + 0);            //  4,718,592 B
    float* rnorm = (float*)(ws + 4718592);      //     16,384 B
    int*   cidx  = (int*)  (ws + 4734976);      //     69,632 B (4 batches)
    int*   nk    = (int*)  (ws + 4804608);      //         32 B
    float* S     = (float*)(ws + 9469952);      // 67,108,864 B (reused as V f16)
    f16*   Ah    = (f16*)  (ws + 76578816);     // 33,554,432 B
    f16*   Rt    = (f16*)  (ws + 110133248);    // 16,777,216 B
    f16*   ybTp  = (f16*)  (ws + 126910464);    // 21,233,664 B (padded, 4 batches)
    f16*   Wt    = (f16*)  (ws + 148144128);    //     73,728 B (end 148,217,856)
    f16*   V     = (f16*)S;                     // S dead after softmax

    prep_w<<<288, 256, 0, stream>>>(conv_w, Wt);
    compact_mask_all<<<4, 256, 0, stream>>>(mask, cidx, nk);
    zero_halo<<<5184, 256, 0, stream>>>(ybTp);
    for (int b = 0; b < 4; ++b) {
        const float* x2b = x2 + (size_t)b * 64 * 4096;
        const float* x1b = x1 + (size_t)b * 128 * 16384;
        const int* cb_idx = cidx + b * 4352;
        const int* nkb = nk + b * 2;
        build_P_norm<<<4096, 64, 0, stream>>>(x2b, Ph, rnorm);
        gemm_score_mfma<<<dim3(32, 32), 256, 0, stream>>>(Ph, cb_idx, rnorm, nkb, S);
        softmax_mask<<<4096, 256, 0, stream>>>(S, nkb, mask_all + (size_t)b * 4096, Ah);
        build_Rt<<<32768, 256, 0, stream>>>(x1b, cb_idx, nkb, Rt);
        gemm_deconv_mfma<<<512, 256, 0, stream>>>(Ah, Rt, nkb, V);
        reconstruct<<<8192, 256, 0, stream>>>(V, ybTp + (size_t)b * PPAD * 128);
    }
    final_conv_mfma<<<1024, 256, 0, stream>>>(ybTp, Wt, conv_b, out);
}

// Round 8
// 750.629 us; speedup vs baseline: 7.3119x; 1.0460x over previous
//
#include <hip/hip_runtime.h>
#include <math.h>

typedef _Float16 f16;
typedef __attribute__((ext_vector_type(8))) _Float16 f16x8;
typedef __attribute__((ext_vector_type(4))) _Float16 f16x4;
typedef __attribute__((ext_vector_type(4))) float f32x4;

#define LPOS 4096      // 64*64 positions / patches
#define KPAT 576       // 64ch * 3*3 patch
#define RPAT 2048      // 128ch * 4*4 raw patch
#define PPAD 20736     // 144*144 padded positions for ybT
#define ROWS 18432     // elems per padded row: 16 chunks * 144 x * 8

#define GLDS(g, l) __builtin_amdgcn_global_load_lds( \
    (const __attribute__((address_space(1))) void*)(g), \
    (__attribute__((address_space(3))) void*)(l), 16, 0, 0)

// ---------------------------------------------------------------------------
// Ph[pos][576] = fp16 3x3x64 patches of x2[b] (zero pad 1); rnorm[pos]
__global__ __launch_bounds__(64) void build_P_norm(const float* __restrict__ x2b,
                                                   f16* __restrict__ Ph,
                                                   float* __restrict__ rnorm) {
    int pos = blockIdx.x;
    int u = pos >> 6, v = pos & 63;
    int tid = threadIdx.x;
    float ss = 0.f;
    for (int k = tid; k < KPAT; k += 64) {
        int c = k / 9, r9 = k % 9;
        int di = r9 / 3, dj = r9 % 3;
        int yy = u + di - 1, xx = v + dj - 1;
        float val = 0.f;
        if (yy >= 0 && yy < 64 && xx >= 0 && xx < 64)
            val = x2b[c * 4096 + yy * 64 + xx];
        Ph[pos * KPAT + k] = (f16)val;
        ss += val * val;
    }
#pragma unroll
    for (int off = 32; off; off >>= 1) ss += __shfl_xor(ss, off, 64);
    if (tid == 0) rnorm[pos] = 1.f / fmaxf(sqrtf(ss), 1e-4f);
}

// ---------------------------------------------------------------------------
// All 4 batches in one launch: block b compacts mask[b] -> cidx[b], nk[b]
__global__ __launch_bounds__(256) void compact_mask_all(const float* __restrict__ mask,
                                                        int* __restrict__ cidx_all,
                                                        int* __restrict__ nk_all) {
    int b = blockIdx.x;
    const float* maskb = mask + (size_t)b * 16384;
    int* cidx = cidx_all + b * 4352;
    int* nk = nk_all + b * 2;
    int tid = threadIdx.x;
    int keep[16];
    int cnt = 0;
#pragma unroll
    for (int e = 0; e < 16; ++e) {
        int pos = tid * 16 + e;
        int pu = pos >> 6, pv = pos & 63;
        float s = 0.f;
        for (int t = 0; t < 4; ++t)
            for (int w = 0; w < 4; ++w) {
                int yy = 2 * pu - 1 + t, xx = 2 * pv - 1 + w;
                if (yy >= 0 && yy < 128 && xx >= 0 && xx < 128)
                    s += maskb[yy * 128 + xx];
            }
        keep[e] = (s == 0.f) ? 1 : 0;
        cnt += keep[e];
    }
    __shared__ int ps[256];
    ps[tid] = cnt;
    __syncthreads();
    for (int off = 1; off < 256; off <<= 1) {
        int v = (tid >= off) ? ps[tid - off] : 0;
        __syncthreads();
        ps[tid] += v;
        __syncthreads();
    }
    int total = ps[255];
    int base = ps[tid] - cnt;   // exclusive prefix
#pragma unroll
    for (int e = 0; e < 16; ++e)
        if (keep[e]) cidx[base++] = tid * 16 + e;
    for (int i = total + tid; i < 4352; i += 256) cidx[i] = 0;
    if (tid == 0) { nk[0] = total; nk[1] = (total + 31) & ~31; }
}

// ---------------------------------------------------------------------------
// Zero the 8-wide halo of the padded chunk-major ybT buffer (all 4 batches)
// layout: ybTp[b][yy 144][chunk q 16][x 144][8 ch]
__global__ __launch_bounds__(256) void zero_halo(f16* __restrict__ ybTp) {
    int idx = blockIdx.x * 256 + threadIdx.x;   // b*331776/4 ... (4*144*144*16 chunks /4q group)
    // idx enumerates (b, yy, xx, q4) where q4 covers 4 chunk-groups of 4
    int b = idx / 331776; if (b >= 4) return;
    int rem = idx % 331776;                     // 144*144*16
    int q = rem & 15, pos = rem >> 4;
    int yy = pos / 144, xx = pos % 144;
    if (yy >= 8 && yy < 136 && xx >= 8 && xx < 136) return;
    *(f16x8*)(ybTp + (size_t)b * PPAD * 128 + (size_t)yy * ROWS + q * 1152 + xx * 8) = (f16x8){};
}

// ---------------------------------------------------------------------------
// S[m][j] = Ph[m] . Ph[cidx[j]] * rnorm[cidx[j]]   (fp16 MFMA, gathered B)
// LDS XOR-swizzle: 16B block cblk of row stored at slot cblk^((row>>1)&3).
__global__ __launch_bounds__(256) void gemm_score_mfma(const f16* __restrict__ Ph,
                                                       const int* __restrict__ cidx,
                                                       const float* __restrict__ rnorm,
                                                       const int* __restrict__ nk,
                                                       float* __restrict__ S) {
    int n0 = blockIdx.x * 128;
    if (n0 >= nk[0]) return;    // fully-masked column tile
    __shared__ f16 Ash[128 * 32], Bsh[128 * 32];
    int tid = threadIdx.x;
    int w = tid >> 6, lane = tid & 63;
    int wy = w >> 1, wx = w & 1;
    int m0 = blockIdx.y * 128;
    f32x4 acc[4][4];
#pragma unroll
    for (int mt = 0; mt < 4; ++mt)
#pragma unroll
        for (int nt = 0; nt < 4; ++nt) acc[mt][nt] = (f32x4){0.f, 0.f, 0.f, 0.f};
    int srow = lane >> 2;                          // 0..15
    int cblk = lane & 3;                           // LDS slot 16B block
    int scol = (cblk ^ ((srow >> 1) & 3)) * 8;     // swizzled global col (elems)
    int dcol = cblk * 8;
    int r = lane & 15, qb = lane >> 4;
    int sw = (r >> 1) & 3;
    int qcol = (qb ^ sw) * 8;                      // de-swizzled read col
    const f16* Asrc[2]; const f16* Bsrc[2]; int ldso[2];
#pragma unroll
    for (int i = 0; i < 2; ++i) {
        int row = w * 32 + i * 16 + srow;
        ldso[i] = row * 32 + dcol;
        Asrc[i] = Ph + (size_t)(m0 + row) * KPAT + scol;
        Bsrc[i] = Ph + (size_t)cidx[n0 + row] * KPAT + scol;
    }
    for (int k0 = 0; k0 < KPAT; k0 += 32) {
#pragma unroll
        for (int i = 0; i < 2; ++i) {
            GLDS(Asrc[i] + k0, Ash + ldso[i]);
            GLDS(Bsrc[i] + k0, Bsh + ldso[i]);
        }
        __syncthreads();
        f16x8 vb[4];
#pragma unroll
        for (int nt = 0; nt < 4; ++nt)
            vb[nt] = *(const f16x8*)&Bsh[(wx * 64 + nt * 16 + r) * 32 + qcol];
#pragma unroll
        for (int mt = 0; mt < 4; ++mt) {
            f16x8 va = *(const f16x8*)&Ash[(wy * 64 + mt * 16 + r) * 32 + qcol];
#pragma unroll
            for (int nt = 0; nt < 4; ++nt)
                acc[mt][nt] = __builtin_amdgcn_mfma_f32_16x16x32_f16(va, vb[nt], acc[mt][nt], 0, 0, 0);
        }
        __syncthreads();
    }
    int qq = lane >> 4;
#pragma unroll
    for (int nt = 0; nt < 4; ++nt) {
        int col = n0 + wx * 64 + nt * 16 + r;
        float rn = rnorm[cidx[col]];
#pragma unroll
        for (int mt = 0; mt < 4; ++mt)
#pragma unroll
            for (int ri = 0; ri < 4; ++ri) {
                int row = m0 + wy * 64 + mt * 16 + qq * 4 + ri;
                S[(size_t)row * LPOS + col] = acc[mt][nt][ri] * rn;
            }
    }
}

// ---------------------------------------------------------------------------
// Masked softmax over compacted columns (float4 reads, f16x4 writes)
__global__ __launch_bounds__(256) void softmax_mask(const float* __restrict__ S,
                                                    const int* __restrict__ nk,
                                                    const float* __restrict__ mab,
                                                    f16* __restrict__ Ah) {
    int pos = blockIdx.x;
    int tid = threadIdx.x;
    int nkeep = nk[0], kpad = nk[1];
    float ma = mab[pos];
    float sc = 10.0f * ma;
    const float4* S4 = (const float4*)(S + (size_t)pos * LPOS);
    float v[16];
    float vmax = (nkeep < LPOS) ? 0.f : -3.0e38f;
#pragma unroll
    for (int i = 0; i < 4; ++i) {
        int jb = (tid + i * 256) * 4;
        float4 x4 = S4[tid + i * 256];
#pragma unroll
        for (int e = 0; e < 4; ++e) {
            float xv = (&x4.x)[e];
            float x = (jb + e < nkeep) ? xv * sc : -3.0e38f;
            v[i * 4 + e] = x;
            vmax = fmaxf(vmax, x);
        }
    }
#pragma unroll
    for (int off = 32; off; off >>= 1) vmax = fmaxf(vmax, __shfl_xor(vmax, off, 64));
    __shared__ float sred[4];
    int wid = tid >> 6;
    if ((tid & 63) == 0) sred[wid] = vmax;
    __syncthreads();
    vmax = fmaxf(fmaxf(sred[0], sred[1]), fmaxf(sred[2], sred[3]));
    __syncthreads();
    float ssum = 0.f;
#pragma unroll
    for (int i = 0; i < 16; ++i) {
        float e = (v[i] > -1.0e37f) ? __expf(v[i] - vmax) : 0.f;
        v[i] = e;
        ssum += e;
    }
#pragma unroll
    for (int off = 32; off; off >>= 1) ssum += __shfl_xor(ssum, off, 64);
    if ((tid & 63) == 0) sred[wid] = ssum;
    __syncthreads();
    float total = sred[0] + sred[1] + sred[2] + sred[3]
                + (float)(LPOS - nkeep) * __expf(-vmax);
    float inv = 1.f / total;
#pragma unroll
    for (int i = 0; i < 4; ++i) {
        int jb = (tid + i * 256) * 4;
        if (jb >= kpad) continue;
        f16x4 h;
#pragma unroll
        for (int e = 0; e < 4; ++e)
            h[e] = (jb + e < nkeep) ? (f16)(v[i * 4 + e] * inv * ma) : (f16)0.f;
        *(f16x4*)(Ah + (size_t)pos * LPOS + jb) = h;
    }
}

// ---------------------------------------------------------------------------
// Rt[n][j] fp16, n = (t*4+s)*128 + c, patch p = cidx[j] (compacted gather)
__global__ __launch_bounds__(256) void build_Rt(const float* __restrict__ x1b,
                                                const int* __restrict__ cidx,
                                                const int* __restrict__ nk,
                                                f16* __restrict__ Rt) {
    int idx = blockIdx.x * 256 + threadIdx.x;   // n*4096 + j
    int j = idx & 4095, n = idx >> 12;
    if (j >= nk[1]) return;
    int p = cidx[j];
    int pu = p >> 6, pv = p & 63;
    int t = (n >> 9) & 3, s = (n >> 7) & 3, c = n & 127;
    int yy = 2 * pu - 1 + t, xx = 2 * pv - 1 + s;
    float val = 0.f;
    if (yy >= 0 && yy < 128 && xx >= 0 && xx < 128)
        val = x1b[c * 16384 + yy * 128 + xx];
    Rt[idx] = (f16)val;
}

// ---------------------------------------------------------------------------
// V[m][n] = sum_{k<kpad} A[m][k] * Bt[n][k]   (fp16 MFMA, dynamic K, fp16 out)
// 1D grid 512: XCD (id&7) owns 4 m-tiles -> A slice (3 MB) L2-resident.
// LDS XOR-swizzled (same scheme as gemm_score_mfma).
__global__ __launch_bounds__(256) void gemm_deconv_mfma(const f16* __restrict__ A,
                                                        const f16* __restrict__ Bt,
                                                        const int* __restrict__ nk,
                                                        f16* __restrict__ V) {
    __shared__ f16 Ash[128 * 32], Bsh[128 * 32];
    int kpad = nk[1];
    int id = blockIdx.x;
    int m0 = ((id & 7) * 4 + ((id >> 3) & 3)) * 128;
    int n0 = (id >> 5) * 128;
    int tid = threadIdx.x;
    int w = tid >> 6, lane = tid & 63;
    int wy = w >> 1, wx = w & 1;
    f32x4 acc[4][4];
#pragma unroll
    for (int mt = 0; mt < 4; ++mt)
#pragma unroll
        for (int nt = 0; nt < 4; ++nt) acc[mt][nt] = (f32x4){0.f, 0.f, 0.f, 0.f};
    int srow = lane >> 2;
    int cblk = lane & 3;
    int scol = (cblk ^ ((srow >> 1) & 3)) * 8;
    int dcol = cblk * 8;
    int r = lane & 15, qb = lane >> 4;
    int sw = (r >> 1) & 3;
    int qcol = (qb ^ sw) * 8;
    for (int k0 = 0; k0 < kpad; k0 += 32) {
#pragma unroll
        for (int i = 0; i < 2; ++i) {
            int row = w * 32 + i * 16 + srow;
            int ldso = row * 32 + dcol;
            GLDS(A + (size_t)(m0 + row) * LPOS + k0 + scol, Ash + ldso);
            GLDS(Bt + (size_t)(n0 + row) * LPOS + k0 + scol, Bsh + ldso);
        }
        __syncthreads();
        f16x8 vb[4];
#pragma unroll
        for (int nt = 0; nt < 4; ++nt)
            vb[nt] = *(const f16x8*)&Bsh[(wx * 64 + nt * 16 + r) * 32 + qcol];
#pragma unroll
        for (int mt = 0; mt < 4; ++mt) {
            f16x8 va = *(const f16x8*)&Ash[(wy * 64 + mt * 16 + r) * 32 + qcol];
#pragma unroll
            for (int nt = 0; nt < 4; ++nt)
                acc[mt][nt] = __builtin_amdgcn_mfma_f32_16x16x32_f16(va, vb[nt], acc[mt][nt], 0, 0, 0);
        }
        __syncthreads();
    }
    int qq = lane >> 4;
#pragma unroll
    for (int mt = 0; mt < 4; ++mt)
#pragma unroll
        for (int nt = 0; nt < 4; ++nt) {
            int col = n0 + wx * 64 + nt * 16 + r;
#pragma unroll
            for (int ri = 0; ri < 4; ++ri) {
                int row = m0 + wy * 64 + mt * 16 + qq * 4 + ri;
                V[(size_t)row * RPAT + col] = (f16)acc[mt][nt][ri];
            }
        }
}

// ---------------------------------------------------------------------------
// reconstruct -> chunk-major padded layout:
// ybTp[b][yy+8][q=c>>3][xx+8][c&7] = 0.25 * sum over valid taps of V
__global__ __launch_bounds__(256) void reconstruct(const f16* __restrict__ V,
                                                   f16* __restrict__ ybTpb) {
    int idx = blockIdx.x * 256 + threadIdx.x;   // p*128 + c
    int c = idx & 127, p = idx >> 7;
    int xx = p & 127, yy = p >> 7;
    float sum = 0.f;
    int tby = (yy & 1) ? 0 : 1;
    int tbx = (xx & 1) ? 0 : 1;
#pragma unroll
    for (int dt = 0; dt < 2; ++dt) {
        int t = tby + 2 * dt;
        int u2 = yy + 1 - t;
        if (u2 < 0 || u2 >= 128) continue;
        int u = u2 >> 1;
#pragma unroll
        for (int ds = 0; ds < 2; ++ds) {
            int s = tbx + 2 * ds;
            int v2 = xx + 1 - s;
            if (v2 < 0 || v2 >= 128) continue;
            int v = v2 >> 1;
            sum += (float)V[(size_t)(u * 64 + v) * RPAT + (t * 4 + s) * 128 + c];
        }
    }
    ybTpb[(size_t)(yy + 8) * ROWS + (c >> 3) * 1152 + (xx + 8) * 8 + (c & 7)] = (f16)(0.25f * sum);
}

// ---------------------------------------------------------------------------
// Wt[g][tap][oc][c] fp16 from conv_w (4,16,128,3,3) fp32
__global__ __launch_bounds__(256) void prep_w(const float* __restrict__ cw,
                                              f16* __restrict__ Wt) {
    int idx = blockIdx.x * 256 + threadIdx.x;
    if (idx >= 4 * 9 * 16 * 128) return;
    int g = idx / 18432, rem = idx % 18432;
    int tap = rem >> 11, oc = (rem >> 7) & 15, c = rem & 127;
    Wt[idx] = (f16)cw[(((g * 16 + oc) * 128 + c) * 9) + tap];
}

// ---------------------------------------------------------------------------
// Tap-decomposed implicit-GEMM grouped dilated conv via MFMA (fp16).
// Chunk-major ybTp: a wave's 16 m-lanes read 16 consecutive 16B blocks
// (dense 256B segments, ~2 cache lines) -> no MSHR fan-out.
// Grid 2048 (8 blocks/CU, 32 waves/CU): block = (b, yhalf via id&7, g, y);
// 4 waves x 32 x-positions each.
__global__ __launch_bounds__(256) void final_conv_mfma(const f16* __restrict__ ybTp,
                                                       const f16* __restrict__ Wt,
                                                       const float* __restrict__ cb,
                                                       float* __restrict__ out) {
    int id = blockIdx.x;
    int p = id & 7;
    int b = p >> 1, yhalf = p & 1;
    int rest = id >> 3;             // 0..255
    int g = rest >> 6;              // 0..3
    int y = yhalf * 64 + (rest & 63);
    int tid = threadIdx.x, w = tid >> 6, lane = tid & 63;
    int xbase = w * 32;
    int r = 1 << g;                 // RATES = 1,2,4,8
    int m = lane & 15, q = lane >> 4;
    const f16* yB = ybTp + (size_t)b * PPAD * 128;
    const f16* Wg = Wt + g * 18432 + m * 128 + q * 8;
    f32x4 acc[2];
    acc[0] = (f32x4){0.f, 0.f, 0.f, 0.f};
    acc[1] = (f32x4){0.f, 0.f, 0.f, 0.f};
#pragma unroll
    for (int tap = 0; tap < 9; ++tap) {
        int dy = (tap / 3 - 1) * r, dx = (tap % 3 - 1) * r;
        const f16* rowb = yB + (size_t)(y + dy + 8) * ROWS + q * 1152
                        + (xbase + m + 8 + dx) * 8;
        const f16* wrow = Wg + tap * 2048;
#pragma unroll
        for (int ks = 0; ks < 4; ++ks) {
            f16x8 bfrag = *(const f16x8*)(wrow + ks * 32);
            f16x8 a0 = *(const f16x8*)(rowb + ks * 4608);
            f16x8 a1 = *(const f16x8*)(rowb + ks * 4608 + 128);
            acc[0] = __builtin_amdgcn_mfma_f32_16x16x32_f16(a0, bfrag, acc[0], 0, 0, 0);
            acc[1] = __builtin_amdgcn_mfma_f32_16x16x32_f16(a1, bfrag, acc[1], 0, 0, 0);
        }
    }
    float bias = cb[g * 16 + m];
    float* orow = out + ((size_t)(b * 64 + g * 16 + m)) * 16384 + (size_t)y * 128;
#pragma unroll
    for (int mt = 0; mt < 2; ++mt)
#pragma unroll
        for (int ri = 0; ri < 4; ++ri) {
            int x = xbase + mt * 16 + q * 4 + ri;
            orow[x] = fmaxf(acc[mt][ri] + bias, 0.f);
        }
}

// ---------------------------------------------------------------------------
extern "C" void kernel_launch(void* const* d_in, const int* in_sizes, int n_in,
                              void* d_out, int out_size, void* d_ws, size_t ws_size,
                              hipStream_t stream) {
    const float* x1 = (const float*)d_in[0];        // (4,128,128,128)
    const float* x2 = (const float*)d_in[1];        // (4,64,64,64)
    const float* mask = (const float*)d_in[2];      // (4,1,128,128)
    const float* mask_all = (const float*)d_in[3];  // (4,1,64,64)
    const float* conv_w = (const float*)d_in[4];    // (4,16,128,3,3)
    const float* conv_b = (const float*)d_in[5];    // (4,16)
    float* out = (float*)d_out;                     // (4,64,128,128)

    char* ws = (char*)d_ws;
    f16*   Ph    = (f16*)  (ws + 0);            //  4,718,592 B
    float* rnorm = (float*)(ws + 4718592);      //     16,384 B
    int*   cidx  = (int*)  (ws + 4734976);      //     69,632 B (4 batches)
    int*   nk    = (int*)  (ws + 4804608);      //         32 B
    float* S     = (float*)(ws + 9469952);      // 67,108,864 B (reused as V f16)
    f16*   Ah    = (f16*)  (ws + 76578816);     // 33,554,432 B
    f16*   Rt    = (f16*)  (ws + 110133248);    // 16,777,216 B
    f16*   ybTp  = (f16*)  (ws + 126910464);    // 21,233,664 B (padded, 4 batches)
    f16*   Wt    = (f16*)  (ws + 148144128);    //     73,728 B (end 148,217,856)
    f16*   V     = (f16*)S;                     // S dead after softmax

    prep_w<<<288, 256, 0, stream>>>(conv_w, Wt);
    compact_mask_all<<<4, 256, 0, stream>>>(mask, cidx, nk);
    zero_halo<<<5184, 256, 0, stream>>>(ybTp);
    for (int b = 0; b < 4; ++b) {
        const float* x2b = x2 + (size_t)b * 64 * 4096;
        const float* x1b = x1 + (size_t)b * 128 * 16384;
        const int* cb_idx = cidx + b * 4352;
        const int* nkb = nk + b * 2;
        build_P_norm<<<4096, 64, 0, stream>>>(x2b, Ph, rnorm);
        gemm_score_mfma<<<dim3(32, 32), 256, 0, stream>>>(Ph, cb_idx, rnorm, nkb, S);
        softmax_mask<<<4096, 256, 0, stream>>>(S, nkb, mask_all + (size_t)b * 4096, Ah);
        build_Rt<<<32768, 256, 0, stream>>>(x1b, cb_idx, nkb, Rt);
        gemm_deconv_mfma<<<512, 256, 0, stream>>>(Ah, Rt, nkb, V);
        reconstruct<<<8192, 256, 0, stream>>>(V, ybTp + (size_t)b * PPAD * 128);
    }
    final_conv_mfma<<<2048, 256, 0, stream>>>(ybTp, Wt, conv_b, out);
}